// Round 1
// baseline (868.926 us; speedup 1.0000x reference)
//
#include <hip/hip_runtime.h>
#include <hip/hip_bf16.h>
#include <math.h>

// MotionFormerBlock fp32 baseline.
// Shapes fixed by the problem: B=8, N=1024, C=DIM=256, MDIM=128, H=8, HD=32,
// MHD=16, HID=1024.
#define C_DIM 256
#define N_PTS 1024
#define B_SZ 8
#define H_N 8
#define MDIM_N 128
#define HID_N 1024
#define EPSV 1e-5f
#define R_TOT 8192              // B*N token rows
#define CN 262144               // C_DIM * N_PTS (per-batch x slab)

// ---------------------------------------------------------------- BN1 stats
// One block per channel c; reduce mean/var over (B,N) = 8192 elems.
// Stores sc = g/sqrt(var+eps), sh = b - mean*sc  ->  xn = x*sc + sh
__global__ __launch_bounds__(256)
void bn1_stats_k(const float* __restrict__ x, const float* __restrict__ g,
                 const float* __restrict__ bb, float* __restrict__ st) {
  int c = blockIdx.x;
  int t = threadIdx.x;
  float s = 0.f, q = 0.f;
  for (int i = 0; i < 32; ++i) {
    int idx = t + i * 256;              // 0..8191
    int b = idx >> 10, n = idx & 1023;
    float v = x[(size_t)b * CN + (size_t)c * N_PTS + n];
    s += v; q += v * v;
  }
  __shared__ float ss[256], sq[256];
  ss[t] = s; sq[t] = q;
  __syncthreads();
  for (int off = 128; off > 0; off >>= 1) {
    if (t < off) { ss[t] += ss[t + off]; sq[t] += sq[t + off]; }
    __syncthreads();
  }
  if (t == 0) {
    float mean = ss[0] * (1.f / 8192.f);
    float var  = sq[0] * (1.f / 8192.f) - mean * mean;
    float sc   = g[c] * rsqrtf(var + EPSV);
    st[c]          = sc;
    st[C_DIM + c]  = bb[c] - mean * sc;
  }
}

// ------------------------------------------- normalize + transpose to tokens
// x [B,C,N] -> xn [B*N, C] with affine; 32x32 LDS tile transpose.
__global__ __launch_bounds__(256)
void norm1_t_k(const float* __restrict__ x, const float* __restrict__ st,
               float* __restrict__ xn) {
  __shared__ float tile[32][33];
  int c0 = blockIdx.x * 32, n0 = blockIdx.y * 32, b = blockIdx.z;
  int tx = threadIdx.x, ty = threadIdx.y;      // block (32,8)
#pragma unroll
  for (int k = 0; k < 4; ++k) {
    int ci = ty + k * 8;
    int c = c0 + ci;
    float v = x[(size_t)b * CN + (size_t)c * N_PTS + n0 + tx];
    tile[ci][tx] = v * st[c] + st[C_DIM + c];
  }
  __syncthreads();
#pragma unroll
  for (int k = 0; k < 4; ++k) {
    int ni = ty + k * 8;
    xn[((size_t)(b * N_PTS + n0 + ni)) * C_DIM + c0 + tx] = tile[tx][ni];
  }
}

// ---------------------------------------------------------------- ce = cor @ cor_w^T
// cor [R,3], cor_w [128,3] -> ce [R,128]
__global__ __launch_bounds__(256)
void ce_k(const float* __restrict__ cor, const float* __restrict__ cw,
          float* __restrict__ ce) {
  int t = threadIdx.x;
  int r = blockIdx.x * 2 + (t >> 7);
  int j = t & 127;
  float c0 = cor[r * 3 + 0], c1 = cor[r * 3 + 1], c2 = cor[r * 3 + 2];
  ce[(size_t)r * MDIM_N + j] =
      c0 * cw[j * 3 + 0] + c1 * cw[j * 3 + 1] + c2 * cw[j * 3 + 2];
}

// ---------------------------------------------------------------- attention
// One thread per query row (per b,h). Online softmax over 1024 keys in 8
// LDS-staged tiles of 128. V' = concat(v[32], ceh[16]) accumulated together.
__global__ __launch_bounds__(256)
void attn_k(const float* __restrict__ qb, const float* __restrict__ kvb,
            const float* __restrict__ ceb, float* __restrict__ av,
            float* __restrict__ cr) {
  int bh = blockIdx.x; int b = bh >> 3, h = bh & 7;
  int row = blockIdx.y * 256 + threadIdx.x;
  const float scale = 0.17677669529663687f;    // 32^-0.5
  float qr[32];
  const float* qp = qb + ((size_t)(b * N_PTS + row)) * C_DIM + h * 32;
#pragma unroll
  for (int d = 0; d < 32; ++d) qr[d] = qp[d] * scale;
  float m = -1e30f, l = 0.f;
  float acc[48];
#pragma unroll
  for (int d = 0; d < 48; ++d) acc[d] = 0.f;
  __shared__ float Ks[128][32];
  __shared__ float Vs[128][48];
  for (int kt = 0; kt < 8; ++kt) {
    int key0 = kt * 128;
#pragma unroll
    for (int e = 0; e < 16; ++e) {             // 4096 K elems
      int idx = threadIdx.x + e * 256;
      int j = idx >> 5, d = idx & 31;
      Ks[j][d] = kvb[((size_t)(b * N_PTS + key0 + j)) * 512 + h * 32 + d];
    }
    for (int e = 0; e < 24; ++e) {             // 6144 V' elems
      int idx = threadIdx.x + e * 256;
      int j = idx / 48, d = idx % 48;
      size_t rk = (size_t)(b * N_PTS + key0 + j);
      float v;
      if (d < 32) v = kvb[rk * 512 + 256 + h * 32 + d];
      else        v = ceb[rk * MDIM_N + h * 16 + (d - 32)];
      Vs[j][d] = v;
    }
    __syncthreads();
    for (int j = 0; j < 128; ++j) {
      float s = 0.f;
#pragma unroll
      for (int d = 0; d < 32; ++d) s += qr[d] * Ks[j][d];
      if (s > m) {                             // rare after warm-up
        float corr = __expf(m - s);
        l *= corr;
#pragma unroll
        for (int d = 0; d < 48; ++d) acc[d] *= corr;
        m = s;
      }
      float p = __expf(s - m);
      l += p;
#pragma unroll
      for (int d = 0; d < 48; ++d) acc[d] += p * Vs[j][d];
    }
    __syncthreads();
  }
  float invl = 1.f / l;
  float* ap = av + ((size_t)(b * N_PTS + row)) * C_DIM + h * 32;
#pragma unroll
  for (int d = 0; d < 32; ++d) ap[d] = acc[d] * invl;
  float* cp = cr + ((size_t)(b * N_PTS + row)) * MDIM_N + h * 16;
#pragma unroll
  for (int d = 0; d < 16; ++d) cp[d] = acc[32 + d] * invl;
}

// ---------------------------------------------------------------- generic GEMM
// out[r,m] = sum_k A'[r,k] * W[m,k]  (+ mode-specific A-load and epilogue)
// MODE 0: plain (q-proj, no bias)
// MODE 1: A rows batch-swapped (kv-proj, no bias)
// MODE 2: out = e0 + acc + bias           (proj + residual -> xn2)
// MODE 3: A = A - A2                      (motion = (cr-ce)@mproj^T + b)
// MODE 4: A-load affine e0/e1 (BN2), epilogue dw(e2,e3) + PReLU(pre)  (fc1)
// MODE 5: epilogue transposed store: out[b,c,n] = e0[b,c,n] + acc + bias (fc2)
#define BM 64
#define BN 64
#define BK 16
template <int MODE>
__global__ __launch_bounds__(256)
void gemm_k(const float* __restrict__ A, const float* __restrict__ A2,
            const float* __restrict__ W, const float* __restrict__ bias,
            float* __restrict__ out, const float* __restrict__ e0,
            const float* __restrict__ e1, const float* __restrict__ e2,
            const float* __restrict__ e3, const float* __restrict__ pre,
            int R, int K, int M) {
  __shared__ float As[BM][BK + 1];
  __shared__ float Ws[BK][BN + 1];
  int tid = threadIdx.x;
  int r0 = blockIdx.y * BM;
  int m0 = blockIdx.x * BN;
  int tx = tid & 15, ty = tid >> 4;
  float acc[4][4] = {};
  for (int kt = 0; kt < K; kt += BK) {
#pragma unroll
    for (int e = 0; e < 4; ++e) {              // A tile 64x16
      int idx = tid + e * 256;
      int i = idx >> 4, kk = idx & 15;
      int r = r0 + i, k = kt + kk;
      float v;
      if (MODE == 1) {
        int b = r >> 10, n = r & 1023;
        int sr = (((b + 4) & 7) << 10) + n;
        v = A[(size_t)sr * K + k];
      } else if (MODE == 3) {
        v = A[(size_t)r * K + k] - A2[(size_t)r * K + k];
      } else if (MODE == 4) {
        v = A[(size_t)r * K + k] * e0[k] + e1[k];
      } else {
        v = A[(size_t)r * K + k];
      }
      As[i][kk] = v;
    }
#pragma unroll
    for (int e = 0; e < 4; ++e) {              // W tile 64x16 -> Ws[k][m]
      int idx = tid + e * 256;
      int mm = idx >> 4, kk = idx & 15;
      Ws[kk][mm] = W[(size_t)(m0 + mm) * K + kt + kk];
    }
    __syncthreads();
#pragma unroll
    for (int kk = 0; kk < BK; ++kk) {
      float a[4], bv[4];
#pragma unroll
      for (int i = 0; i < 4; ++i) a[i] = As[ty * 4 + i][kk];
#pragma unroll
      for (int j = 0; j < 4; ++j) bv[j] = Ws[kk][tx * 4 + j];
#pragma unroll
      for (int i = 0; i < 4; ++i)
#pragma unroll
        for (int j = 0; j < 4; ++j) acc[i][j] += a[i] * bv[j];
    }
    __syncthreads();
  }
  float a_pre = (MODE == 4) ? pre[0] : 0.f;
#pragma unroll
  for (int i = 0; i < 4; ++i) {
    int r = r0 + ty * 4 + i;
#pragma unroll
    for (int j = 0; j < 4; ++j) {
      int mm = m0 + tx * 4 + j;
      float v = acc[i][j];
      if (MODE == 0 || MODE == 1) {
        out[(size_t)r * M + mm] = v;
      } else if (MODE == 2) {
        out[(size_t)r * M + mm] = e0[(size_t)r * M + mm] + v + bias[mm];
      } else if (MODE == 3) {
        out[(size_t)r * M + mm] = v + bias[mm];
      } else if (MODE == 4) {
        v += bias[mm];
        v = v * e2[mm] + e3[mm];
        out[(size_t)r * M + mm] = v >= 0.f ? v : a_pre * v;
      } else {  // MODE 5: transposed residual store into [B,C,N]
        int b = r >> 10, n = r & 1023;
        size_t oi = (size_t)b * CN + (size_t)mm * N_PTS + n;
        out[oi] = e0[oi] + v + bias[mm];
      }
    }
  }
}

// ---------------------------------------------------------------- BN2 stats
__global__ __launch_bounds__(256)
void bn2_stats_k(const float* __restrict__ xn2, float* __restrict__ raw) {
  int t = threadIdx.x;
  float s = 0.f, q = 0.f;
  int r0 = blockIdx.x * 128;
  for (int i = 0; i < 128; ++i) {
    float v = xn2[(size_t)(r0 + i) * C_DIM + t];
    s += v; q += v * v;
  }
  atomicAdd(&raw[t], s);
  atomicAdd(&raw[C_DIM + t], q);
}

__global__ __launch_bounds__(256)
void bn2_final_k(const float* __restrict__ raw, const float* __restrict__ g,
                 const float* __restrict__ bb, float* __restrict__ st) {
  int c = threadIdx.x;
  float mean = raw[c] * (1.f / 8192.f);
  float var  = raw[C_DIM + c] * (1.f / 8192.f) - mean * mean;
  float sc   = g[c] * rsqrtf(var + EPSV);
  st[c]         = sc;
  st[C_DIM + c] = bb[c] - mean * sc;
}

extern "C" void kernel_launch(void* const* d_in, const int* in_sizes, int n_in,
                              void* d_out, int out_size, void* d_ws,
                              size_t ws_size, hipStream_t stream) {
  const float* x       = (const float*)d_in[0];
  const float* cor     = (const float*)d_in[1];
  const float* q_w     = (const float*)d_in[2];
  const float* kv_w    = (const float*)d_in[3];
  const float* cor_w   = (const float*)d_in[4];
  const float* proj_w  = (const float*)d_in[5];
  const float* proj_b  = (const float*)d_in[6];
  const float* mproj_w = (const float*)d_in[7];
  const float* mproj_b = (const float*)d_in[8];
  const float* g1      = (const float*)d_in[9];
  const float* b1      = (const float*)d_in[10];
  const float* g2      = (const float*)d_in[11];
  const float* b2      = (const float*)d_in[12];
  const float* fc1_w   = (const float*)d_in[13];
  const float* fc1_b   = (const float*)d_in[14];
  const float* dw_w    = (const float*)d_in[15];
  const float* dw_b    = (const float*)d_in[16];
  const float* prelu   = (const float*)d_in[17];
  const float* fc2_w   = (const float*)d_in[18];
  const float* fc2_b   = (const float*)d_in[19];

  // workspace layout (floats); h overlays the dead q/kv/ce/av region
  float* ws   = (float*)d_ws;
  float* xn   = ws;                  // 2M floats
  float* qb   = ws + 2097152;        // 2M
  float* kvb  = ws + 4194304;        // 4M
  float* ceb  = ws + 8388608;        // 1M
  float* av   = ws + 9437184;        // 2M
  float* crb  = ws + 11534336;       // 1M
  float* xn2  = ws + 12582912;       // 2M
  float* st1  = ws + 14680064;       // 512
  float* raw2 = st1 + 512;           // 512
  float* st2  = st1 + 1024;          // 512
  float* hb   = qb;                  // overlay, 8M floats (fc1 output)
  float* out0 = (float*)d_out;             // x_out [8,256,1024]
  float* out1 = out0 + 2097152;            // motion [8,1024,128]

  hipMemsetAsync(raw2, 0, 512 * sizeof(float), stream);

  bn1_stats_k<<<256, 256, 0, stream>>>(x, g1, b1, st1);
  norm1_t_k<<<dim3(8, 32, 8), dim3(32, 8), 0, stream>>>(x, st1, xn);

  // q = xn @ q_w^T ; kv = xr @ kv_w^T (row-swapped A)
  gemm_k<0><<<dim3(4, 128), 256, 0, stream>>>(
      xn, nullptr, q_w, nullptr, qb, nullptr, nullptr, nullptr, nullptr,
      nullptr, R_TOT, 256, 256);
  gemm_k<1><<<dim3(8, 128), 256, 0, stream>>>(
      xn, nullptr, kv_w, nullptr, kvb, nullptr, nullptr, nullptr, nullptr,
      nullptr, R_TOT, 256, 512);
  ce_k<<<4096, 256, 0, stream>>>(cor, cor_w, ceb);

  attn_k<<<dim3(64, 4), 256, 0, stream>>>(qb, kvb, ceb, av, crb);

  // xn2 = xn + av @ proj_w^T + proj_b
  gemm_k<2><<<dim3(4, 128), 256, 0, stream>>>(
      av, nullptr, proj_w, proj_b, xn2, xn, nullptr, nullptr, nullptr, nullptr,
      R_TOT, 256, 256);
  // motion = (cr - ce) @ mproj_w^T + mproj_b
  gemm_k<3><<<dim3(2, 128), 256, 0, stream>>>(
      crb, ceb, mproj_w, mproj_b, out1, nullptr, nullptr, nullptr, nullptr,
      nullptr, R_TOT, 128, 128);

  bn2_stats_k<<<64, 256, 0, stream>>>(xn2, raw2);
  bn2_final_k<<<1, 256, 0, stream>>>(raw2, g2, b2, st2);

  // h = prelu(dw(bn2(xn2) @ fc1_w^T + fc1_b))
  gemm_k<4><<<dim3(16, 128), 256, 0, stream>>>(
      xn2, nullptr, fc1_w, fc1_b, hb, st2, st2 + 256, dw_w, dw_b, prelu,
      R_TOT, 256, HID_N);
  // x_out = x + (h @ fc2_w^T + fc2_b)^T
  gemm_k<5><<<dim3(4, 128), 256, 0, stream>>>(
      hb, nullptr, fc2_w, fc2_b, out0, x, nullptr, nullptr, nullptr, nullptr,
      R_TOT, HID_N, 256);
}

// Round 2
// 447.527 us; speedup vs baseline: 1.9416x; 1.9416x over previous
//
#include <hip/hip_runtime.h>
#include <hip/hip_bf16.h>
#include <math.h>

// MotionFormerBlock: fp32 GEMMs + bf16-MFMA flash attention.
// Shapes fixed: B=8, N=1024, C=DIM=256, MDIM=128, H=8, HD=32, MHD=16, HID=1024.
#define C_DIM 256
#define N_PTS 1024
#define B_SZ 8
#define H_N 8
#define MDIM_N 128
#define HID_N 1024
#define EPSV 1e-5f
#define R_TOT 8192              // B*N token rows
#define CN 262144               // C_DIM * N_PTS (per-batch x slab)

typedef __bf16 bf16x8 __attribute__((ext_vector_type(8)));
typedef float f32x4 __attribute__((ext_vector_type(4)));

__device__ inline unsigned pk2(float a, float b) {
  union { unsigned u; __bf16 h[2]; } z;
  z.h[0] = (__bf16)a; z.h[1] = (__bf16)b;
  return z.u;
}

// ---------------------------------------------------------------- BN1 stats
__global__ __launch_bounds__(256)
void bn1_stats_k(const float* __restrict__ x, const float* __restrict__ g,
                 const float* __restrict__ bb, float* __restrict__ st) {
  int c = blockIdx.x;
  int t = threadIdx.x;
  float s = 0.f, q = 0.f;
  for (int i = 0; i < 32; ++i) {
    int idx = t + i * 256;
    int b = idx >> 10, n = idx & 1023;
    float v = x[(size_t)b * CN + (size_t)c * N_PTS + n];
    s += v; q += v * v;
  }
  __shared__ float ss[256], sq[256];
  ss[t] = s; sq[t] = q;
  __syncthreads();
  for (int off = 128; off > 0; off >>= 1) {
    if (t < off) { ss[t] += ss[t + off]; sq[t] += sq[t + off]; }
    __syncthreads();
  }
  if (t == 0) {
    float mean = ss[0] * (1.f / 8192.f);
    float var  = sq[0] * (1.f / 8192.f) - mean * mean;
    float sc   = g[c] * rsqrtf(var + EPSV);
    st[c]          = sc;
    st[C_DIM + c]  = bb[c] - mean * sc;
  }
}

// ------------------------------------------- normalize + transpose to tokens
__global__ __launch_bounds__(256)
void norm1_t_k(const float* __restrict__ x, const float* __restrict__ st,
               float* __restrict__ xn) {
  __shared__ float tile[32][33];
  int c0 = blockIdx.x * 32, n0 = blockIdx.y * 32, b = blockIdx.z;
  int tx = threadIdx.x, ty = threadIdx.y;
#pragma unroll
  for (int k = 0; k < 4; ++k) {
    int ci = ty + k * 8;
    int c = c0 + ci;
    float v = x[(size_t)b * CN + (size_t)c * N_PTS + n0 + tx];
    tile[ci][tx] = v * st[c] + st[C_DIM + c];
  }
  __syncthreads();
#pragma unroll
  for (int k = 0; k < 4; ++k) {
    int ni = ty + k * 8;
    xn[((size_t)(b * N_PTS + n0 + ni)) * C_DIM + c0 + tx] = tile[tx][ni];
  }
}

// ---------------------------------------------------------------- ce = cor @ cor_w^T
__global__ __launch_bounds__(256)
void ce_k(const float* __restrict__ cor, const float* __restrict__ cw,
          float* __restrict__ ce) {
  int t = threadIdx.x;
  int r = blockIdx.x * 2 + (t >> 7);
  int j = t & 127;
  float c0 = cor[r * 3 + 0], c1 = cor[r * 3 + 1], c2 = cor[r * 3 + 2];
  ce[(size_t)r * MDIM_N + j] =
      c0 * cw[j * 3 + 0] + c1 * cw[j * 3 + 1] + c2 * cw[j * 3 + 2];
}

// ---------------------------------------------------------------- MFMA attention
// Block: 256 thr = 4 waves, one (b,h); each wave owns 32 query rows
// (blockIdx.y selects the 128-row slice). KV tiles of 64 keys; V' = [v | ceh]
// (48 dims) staged transposed. Online softmax; P re-shaped via per-wave LDS.
__global__ __launch_bounds__(256)
void attn_k(const float* __restrict__ qb, const float* __restrict__ kvb,
            const float* __restrict__ ceb, float* __restrict__ av,
            float* __restrict__ cr) {
  __shared__ __bf16 KsV[64][40];      // [key][d], pad 40 (80 B rows)
  __shared__ __bf16 VtV[48][72];      // [dv][key], pad 72 (144 B rows)
  __shared__ float  Pbuf[4][32][68];  // per-wave P tile, pad 68

  int bh = blockIdx.x; int b = bh >> 3, h = bh & 7;
  int t = threadIdx.x;
  int w = t >> 6, lane = t & 63;
  int l15 = lane & 15, g = lane >> 4;
  const float scale = 0.17677669529663687f;  // 32^-0.5

  // Q fragments (A operand, M=32 rows -> 2 m-tiles): lane holds row l15+16mt,
  // d = g*8 + j.
  int qrow0 = b * N_PTS + blockIdx.y * 128 + w * 32;
  bf16x8 aq[2];
#pragma unroll
  for (int mt = 0; mt < 2; ++mt) {
    const float* qp =
        &qb[(size_t)(qrow0 + mt * 16 + l15) * C_DIM + h * 32 + g * 8];
    float4 q0 = *(const float4*)qp;
    float4 q1 = *(const float4*)(qp + 4);
    bf16x8 a;
    a[0] = (__bf16)(q0.x * scale); a[1] = (__bf16)(q0.y * scale);
    a[2] = (__bf16)(q0.z * scale); a[3] = (__bf16)(q0.w * scale);
    a[4] = (__bf16)(q1.x * scale); a[5] = (__bf16)(q1.y * scale);
    a[6] = (__bf16)(q1.z * scale); a[7] = (__bf16)(q1.w * scale);
    aq[mt] = a;
  }

  float mrun[2][4], lrun[2][4];
  f32x4 accf[2][3];
#pragma unroll
  for (int mt = 0; mt < 2; ++mt)
#pragma unroll
    for (int r = 0; r < 4; ++r) { mrun[mt][r] = -1e30f; lrun[mt][r] = 0.f; }
#pragma unroll
  for (int mt = 0; mt < 2; ++mt)
#pragma unroll
    for (int nt = 0; nt < 3; ++nt) accf[mt][nt] = (f32x4){0.f, 0.f, 0.f, 0.f};

  int vdv = t % 48;                 // V'-staging assignment (t<192)
  int vkb = (t / 48) * 16;

  for (int kt = 0; kt < 16; ++kt) {
    int key0 = kt * 64;
    __syncthreads();                // previous tile fully consumed
    // ---- stage K tile: 64 keys x 32 d (packed bf16 pairs)
#pragma unroll
    for (int e = 0; e < 4; ++e) {
      int idx = t + e * 256;        // 0..1023
      int j = idx >> 4, p = idx & 15;
      float2 kv2 = *(const float2*)&kvb[(size_t)(b * N_PTS + key0 + j) * 512 +
                                        h * 32 + 2 * p];
      *(unsigned*)&KsV[j][2 * p] = pk2(kv2.x, kv2.y);
    }
    // ---- stage V' transposed: 48 dv x 64 keys
    if (t < 192) {
      int dvo = vdv;
#pragma unroll
      for (int kk = 0; kk < 16; kk += 2) {
        size_t kr0 = (size_t)(b * N_PTS + key0 + vkb + kk);
        float v0, v1;
        if (dvo < 32) {
          v0 = kvb[kr0 * 512 + 256 + h * 32 + dvo];
          v1 = kvb[(kr0 + 1) * 512 + 256 + h * 32 + dvo];
        } else {
          v0 = ceb[kr0 * MDIM_N + h * 16 + dvo - 32];
          v1 = ceb[(kr0 + 1) * MDIM_N + h * 16 + dvo - 32];
        }
        *(unsigned*)&VtV[dvo][vkb + kk] = pk2(v0, v1);
      }
    }
    __syncthreads();

    // ---- S = Q K^T : 2 m-tiles x 4 n-tiles, K(d)=32 in one MFMA
    float sv[2][4][4];
#pragma unroll
    for (int nt = 0; nt < 4; ++nt) {
      bf16x8 bk = *(const bf16x8*)&KsV[nt * 16 + l15][g * 8];
      f32x4 z = (f32x4){0.f, 0.f, 0.f, 0.f};
      f32x4 s0 = __builtin_amdgcn_mfma_f32_16x16x32_bf16(aq[0], bk, z, 0, 0, 0);
      f32x4 s1 = __builtin_amdgcn_mfma_f32_16x16x32_bf16(aq[1], bk, z, 0, 0, 0);
#pragma unroll
      for (int r = 0; r < 4; ++r) { sv[0][nt][r] = s0[r]; sv[1][nt][r] = s1[r]; }
    }

    // ---- online softmax stats + P write (per q-row = (mt, reg))
#pragma unroll
    for (int mt = 0; mt < 2; ++mt) {
#pragma unroll
      for (int r = 0; r < 4; ++r) {
        float tm = fmaxf(fmaxf(sv[mt][0][r], sv[mt][1][r]),
                         fmaxf(sv[mt][2][r], sv[mt][3][r]));
#pragma unroll
        for (int o = 1; o <= 8; o <<= 1) tm = fmaxf(tm, __shfl_xor(tm, o));
        float nm = fmaxf(mrun[mt][r], tm);
        float corr = __expf(mrun[mt][r] - nm);
        mrun[mt][r] = nm;
        float rs = 0.f;
#pragma unroll
        for (int nt = 0; nt < 4; ++nt) {
          float p = __expf(sv[mt][nt][r] - nm);
          sv[mt][nt][r] = p;
          rs += p;
        }
#pragma unroll
        for (int o = 1; o <= 8; o <<= 1) rs += __shfl_xor(rs, o);
        lrun[mt][r] = lrun[mt][r] * corr + rs;
#pragma unroll
        for (int nt = 0; nt < 3; ++nt) accf[mt][nt][r] *= corr;
        int prow = mt * 16 + g * 4 + r;
#pragma unroll
        for (int nt = 0; nt < 4; ++nt)
          Pbuf[w][prow][nt * 16 + l15] = sv[mt][nt][r];
      }
    }

    // ---- reload P as A fragments (wave-internal LDS; no barrier needed)
    bf16x8 ap[2][2];
#pragma unroll
    for (int mt = 0; mt < 2; ++mt)
#pragma unroll
      for (int kc = 0; kc < 2; ++kc) {
        const float* pp = &Pbuf[w][mt * 16 + l15][kc * 32 + g * 8];
        float4 x0 = *(const float4*)pp;
        float4 x1 = *(const float4*)(pp + 4);
        bf16x8 a;
        a[0] = (__bf16)x0.x; a[1] = (__bf16)x0.y;
        a[2] = (__bf16)x0.z; a[3] = (__bf16)x0.w;
        a[4] = (__bf16)x1.x; a[5] = (__bf16)x1.y;
        a[6] = (__bf16)x1.z; a[7] = (__bf16)x1.w;
        ap[mt][kc] = a;
      }

    // ---- PV: out[32 x 48] += P[32 x 64] V'[64 x 48]
#pragma unroll
    for (int nt = 0; nt < 3; ++nt)
#pragma unroll
      for (int kc = 0; kc < 2; ++kc) {
        bf16x8 bv = *(const bf16x8*)&VtV[nt * 16 + l15][kc * 32 + g * 8];
        accf[0][nt] = __builtin_amdgcn_mfma_f32_16x16x32_bf16(
            ap[0][kc], bv, accf[0][nt], 0, 0, 0);
        accf[1][nt] = __builtin_amdgcn_mfma_f32_16x16x32_bf16(
            ap[1][kc], bv, accf[1][nt], 0, 0, 0);
      }
  }

  // ---- epilogue: normalize, scatter to av (dv<32) and cr (dv>=32)
#pragma unroll
  for (int mt = 0; mt < 2; ++mt)
#pragma unroll
    for (int r = 0; r < 4; ++r) {
      float inv = 1.f / lrun[mt][r];
      int row = qrow0 + mt * 16 + g * 4 + r;
      av[(size_t)row * C_DIM + h * 32 + l15]      = accf[mt][0][r] * inv;
      av[(size_t)row * C_DIM + h * 32 + 16 + l15] = accf[mt][1][r] * inv;
      cr[(size_t)row * MDIM_N + h * 16 + l15]     = accf[mt][2][r] * inv;
    }
}

// ---------------------------------------------------------------- generic GEMM
#define BM 64
#define BN 64
#define BK 16
template <int MODE>
__global__ __launch_bounds__(256)
void gemm_k(const float* __restrict__ A, const float* __restrict__ A2,
            const float* __restrict__ W, const float* __restrict__ bias,
            float* __restrict__ out, const float* __restrict__ e0,
            const float* __restrict__ e1, const float* __restrict__ e2,
            const float* __restrict__ e3, const float* __restrict__ pre,
            int R, int K, int M) {
  __shared__ float As[BM][BK + 1];
  __shared__ float Ws[BK][BN + 1];
  int tid = threadIdx.x;
  int r0 = blockIdx.y * BM;
  int m0 = blockIdx.x * BN;
  int tx = tid & 15, ty = tid >> 4;
  float acc[4][4] = {};
  for (int kt = 0; kt < K; kt += BK) {
#pragma unroll
    for (int e = 0; e < 4; ++e) {
      int idx = tid + e * 256;
      int i = idx >> 4, kk = idx & 15;
      int r = r0 + i, k = kt + kk;
      float v;
      if (MODE == 1) {
        int b = r >> 10, n = r & 1023;
        int sr = (((b + 4) & 7) << 10) + n;
        v = A[(size_t)sr * K + k];
      } else if (MODE == 3) {
        v = A[(size_t)r * K + k] - A2[(size_t)r * K + k];
      } else if (MODE == 4) {
        v = A[(size_t)r * K + k] * e0[k] + e1[k];
      } else {
        v = A[(size_t)r * K + k];
      }
      As[i][kk] = v;
    }
#pragma unroll
    for (int e = 0; e < 4; ++e) {
      int idx = tid + e * 256;
      int mm = idx >> 4, kk = idx & 15;
      Ws[kk][mm] = W[(size_t)(m0 + mm) * K + kt + kk];
    }
    __syncthreads();
#pragma unroll
    for (int kk = 0; kk < BK; ++kk) {
      float a[4], bv[4];
#pragma unroll
      for (int i = 0; i < 4; ++i) a[i] = As[ty * 4 + i][kk];
#pragma unroll
      for (int j = 0; j < 4; ++j) bv[j] = Ws[kk][tx * 4 + j];
#pragma unroll
      for (int i = 0; i < 4; ++i)
#pragma unroll
        for (int j = 0; j < 4; ++j) acc[i][j] += a[i] * bv[j];
    }
    __syncthreads();
  }
  float a_pre = (MODE == 4) ? pre[0] : 0.f;
#pragma unroll
  for (int i = 0; i < 4; ++i) {
    int r = r0 + ty * 4 + i;
#pragma unroll
    for (int j = 0; j < 4; ++j) {
      int mm = m0 + tx * 4 + j;
      float v = acc[i][j];
      if (MODE == 0 || MODE == 1) {
        out[(size_t)r * M + mm] = v;
      } else if (MODE == 2) {
        out[(size_t)r * M + mm] = e0[(size_t)r * M + mm] + v + bias[mm];
      } else if (MODE == 3) {
        out[(size_t)r * M + mm] = v + bias[mm];
      } else if (MODE == 4) {
        v += bias[mm];
        v = v * e2[mm] + e3[mm];
        out[(size_t)r * M + mm] = v >= 0.f ? v : a_pre * v;
      } else {
        int b = r >> 10, n = r & 1023;
        size_t oi = (size_t)b * CN + (size_t)mm * N_PTS + n;
        out[oi] = e0[oi] + v + bias[mm];
      }
    }
  }
}

// ---------------------------------------------------------------- BN2 stats
__global__ __launch_bounds__(256)
void bn2_stats_k(const float* __restrict__ xn2, float* __restrict__ raw) {
  int t = threadIdx.x;
  float s = 0.f, q = 0.f;
  int r0 = blockIdx.x * 128;
  for (int i = 0; i < 128; ++i) {
    float v = xn2[(size_t)(r0 + i) * C_DIM + t];
    s += v; q += v * v;
  }
  atomicAdd(&raw[t], s);
  atomicAdd(&raw[C_DIM + t], q);
}

__global__ __launch_bounds__(256)
void bn2_final_k(const float* __restrict__ raw, const float* __restrict__ g,
                 const float* __restrict__ bb, float* __restrict__ st) {
  int c = threadIdx.x;
  float mean = raw[c] * (1.f / 8192.f);
  float var  = raw[C_DIM + c] * (1.f / 8192.f) - mean * mean;
  float sc   = g[c] * rsqrtf(var + EPSV);
  st[c]         = sc;
  st[C_DIM + c] = bb[c] - mean * sc;
}

extern "C" void kernel_launch(void* const* d_in, const int* in_sizes, int n_in,
                              void* d_out, int out_size, void* d_ws,
                              size_t ws_size, hipStream_t stream) {
  const float* x       = (const float*)d_in[0];
  const float* cor     = (const float*)d_in[1];
  const float* q_w     = (const float*)d_in[2];
  const float* kv_w    = (const float*)d_in[3];
  const float* cor_w   = (const float*)d_in[4];
  const float* proj_w  = (const float*)d_in[5];
  const float* proj_b  = (const float*)d_in[6];
  const float* mproj_w = (const float*)d_in[7];
  const float* mproj_b = (const float*)d_in[8];
  const float* g1      = (const float*)d_in[9];
  const float* b1      = (const float*)d_in[10];
  const float* g2      = (const float*)d_in[11];
  const float* b2      = (const float*)d_in[12];
  const float* fc1_w   = (const float*)d_in[13];
  const float* fc1_b   = (const float*)d_in[14];
  const float* dw_w    = (const float*)d_in[15];
  const float* dw_b    = (const float*)d_in[16];
  const float* prelu   = (const float*)d_in[17];
  const float* fc2_w   = (const float*)d_in[18];
  const float* fc2_b   = (const float*)d_in[19];

  float* ws   = (float*)d_ws;
  float* xn   = ws;                  // 2M floats
  float* qb   = ws + 2097152;        // 2M
  float* kvb  = ws + 4194304;        // 4M
  float* ceb  = ws + 8388608;        // 1M
  float* av   = ws + 9437184;        // 2M
  float* crb  = ws + 11534336;       // 1M
  float* xn2  = ws + 12582912;       // 2M
  float* st1  = ws + 14680064;       // 512
  float* raw2 = st1 + 512;           // 512
  float* st2  = st1 + 1024;          // 512
  float* hb   = qb;                  // overlay (fc1 output)
  float* out0 = (float*)d_out;
  float* out1 = out0 + 2097152;

  hipMemsetAsync(raw2, 0, 512 * sizeof(float), stream);

  bn1_stats_k<<<256, 256, 0, stream>>>(x, g1, b1, st1);
  norm1_t_k<<<dim3(8, 32, 8), dim3(32, 8), 0, stream>>>(x, st1, xn);

  gemm_k<0><<<dim3(4, 128), 256, 0, stream>>>(
      xn, nullptr, q_w, nullptr, qb, nullptr, nullptr, nullptr, nullptr,
      nullptr, R_TOT, 256, 256);
  gemm_k<1><<<dim3(8, 128), 256, 0, stream>>>(
      xn, nullptr, kv_w, nullptr, kvb, nullptr, nullptr, nullptr, nullptr,
      nullptr, R_TOT, 256, 512);
  ce_k<<<4096, 256, 0, stream>>>(cor, cor_w, ceb);

  attn_k<<<dim3(64, 8), 256, 0, stream>>>(qb, kvb, ceb, av, crb);

  gemm_k<2><<<dim3(4, 128), 256, 0, stream>>>(
      av, nullptr, proj_w, proj_b, xn2, xn, nullptr, nullptr, nullptr, nullptr,
      R_TOT, 256, 256);
  gemm_k<3><<<dim3(2, 128), 256, 0, stream>>>(
      crb, ceb, mproj_w, mproj_b, out1, nullptr, nullptr, nullptr, nullptr,
      nullptr, R_TOT, 128, 128);

  bn2_stats_k<<<64, 256, 0, stream>>>(xn2, raw2);
  bn2_final_k<<<1, 256, 0, stream>>>(raw2, g2, b2, st2);

  gemm_k<4><<<dim3(16, 128), 256, 0, stream>>>(
      xn2, nullptr, fc1_w, fc1_b, hb, st2, st2 + 256, dw_w, dw_b, prelu,
      R_TOT, 256, HID_N);
  gemm_k<5><<<dim3(4, 128), 256, 0, stream>>>(
      hb, nullptr, fc2_w, fc2_b, out0, x, nullptr, nullptr, nullptr, nullptr,
      R_TOT, HID_N, 256);
}

// Round 3
// 281.099 us; speedup vs baseline: 3.0912x; 1.5921x over previous
//
#include <hip/hip_runtime.h>
#include <hip/hip_bf16.h>
#include <math.h>

// MotionFormerBlock: bf16 MFMA GEMMs + bf16 MFMA flash attention.
// Shapes fixed: B=8, N=1024, C=DIM=256, MDIM=128, H=8, HD=32, MHD=16, HID=1024.
#define C_DIM 256
#define N_PTS 1024
#define H_N 8
#define MDIM_N 128
#define HID_N 1024
#define EPSV 1e-5f
#define R_TOT 8192
#define CN 262144               // C_DIM * N_PTS

typedef __bf16 bf16x8 __attribute__((ext_vector_type(8)));
typedef float f32x4 __attribute__((ext_vector_type(4)));

__device__ inline unsigned short bfu(float f) {
  union { __bf16 h; unsigned short u; } c;
  c.h = (__bf16)f;
  return c.u;
}

// ---------------------------------------------------------------- weight cvt
// All six weight matrices fp32 -> bf16 in one kernel. float4 granularity.
// cum (f4 units): q 16384 | kv 49152 | p 65536 | m 69632 | f1 135168 | f2 200704
__global__ __launch_bounds__(256)
void wcvt_k(const float* __restrict__ s0, const float* __restrict__ s1,
            const float* __restrict__ s2, const float* __restrict__ s3,
            const float* __restrict__ s4, const float* __restrict__ s5,
            __bf16* d0, __bf16* d1, __bf16* d2, __bf16* d3, __bf16* d4,
            __bf16* d5) {
  int i = blockIdx.x * 256 + threadIdx.x;
  const float* s; __bf16* d; int off;
  if      (i <  16384) { s = s0; d = d0; off = 0; }
  else if (i <  49152) { s = s1; d = d1; off = 16384; }
  else if (i <  65536) { s = s2; d = d2; off = 49152; }
  else if (i <  69632) { s = s3; d = d3; off = 65536; }
  else if (i < 135168) { s = s4; d = d4; off = 69632; }
  else                 { s = s5; d = d5; off = 135168; }
  int j = i - off;
  float4 v = ((const float4*)s)[j];
  ushort4 u;
  u.x = bfu(v.x); u.y = bfu(v.y); u.z = bfu(v.z); u.w = bfu(v.w);
  ((ushort4*)d)[j] = u;
}

// ---------------------------------------------------------------- BN1 stats
__global__ __launch_bounds__(256)
void bn1_stats_k(const float* __restrict__ x, const float* __restrict__ g,
                 const float* __restrict__ bb, float* __restrict__ st) {
  int c = blockIdx.x;
  int t = threadIdx.x;
  float s = 0.f, q = 0.f;
  for (int i = 0; i < 32; ++i) {
    int idx = t + i * 256;
    int b = idx >> 10, n = idx & 1023;
    float v = x[(size_t)b * CN + (size_t)c * N_PTS + n];
    s += v; q += v * v;
  }
  __shared__ float ss[256], sq[256];
  ss[t] = s; sq[t] = q;
  __syncthreads();
  for (int off = 128; off > 0; off >>= 1) {
    if (t < off) { ss[t] += ss[t + off]; sq[t] += sq[t + off]; }
    __syncthreads();
  }
  if (t == 0) {
    float mean = ss[0] * (1.f / 8192.f);
    float var  = sq[0] * (1.f / 8192.f) - mean * mean;
    float sc   = g[c] * rsqrtf(var + EPSV);
    st[c]          = sc;
    st[C_DIM + c]  = bb[c] - mean * sc;
  }
}

// ------------------------------------------- normalize + transpose to tokens
// writes fp32 xn (residual use) and bf16 xnb (GEMM A-operand)
__global__ __launch_bounds__(256)
void norm1_t_k(const float* __restrict__ x, const float* __restrict__ st,
               float* __restrict__ xn, __bf16* __restrict__ xnb) {
  __shared__ float tile[32][33];
  int c0 = blockIdx.x * 32, n0 = blockIdx.y * 32, b = blockIdx.z;
  int tx = threadIdx.x, ty = threadIdx.y;
#pragma unroll
  for (int k = 0; k < 4; ++k) {
    int ci = ty + k * 8;
    int c = c0 + ci;
    float v = x[(size_t)b * CN + (size_t)c * N_PTS + n0 + tx];
    tile[ci][tx] = v * st[c] + st[C_DIM + c];
  }
  __syncthreads();
#pragma unroll
  for (int k = 0; k < 4; ++k) {
    int ni = ty + k * 8;
    size_t o = ((size_t)(b * N_PTS + n0 + ni)) * C_DIM + c0 + tx;
    float v = tile[tx][ni];
    xn[o] = v;
    xnb[o] = (__bf16)v;
  }
}

// ---------------------------------------------------------------- ce = cor @ cor_w^T
__global__ __launch_bounds__(256)
void ce_k(const float* __restrict__ cor, const float* __restrict__ cw,
          float* __restrict__ ce) {
  int t = threadIdx.x;
  int r = blockIdx.x * 2 + (t >> 7);
  int j = t & 127;
  float c0 = cor[r * 3 + 0], c1 = cor[r * 3 + 1], c2 = cor[r * 3 + 2];
  ce[(size_t)r * MDIM_N + j] =
      c0 * cw[j * 3 + 0] + c1 * cw[j * 3 + 1] + c2 * cw[j * 3 + 2];
}

// ---------------------------------------------------------------- MFMA attention
// 4 waves/block, one (b,h); wave owns 32 q-rows. Outputs bf16 av and
// bf16 dmc = cr - ce (motion GEMM A-operand pre-fused).
__global__ __launch_bounds__(256)
void attn_k(const __bf16* __restrict__ qb, const __bf16* __restrict__ kvb,
            const float* __restrict__ ceb, __bf16* __restrict__ av,
            __bf16* __restrict__ dmc) {
  __shared__ __bf16 KsV[64][40];
  __shared__ __bf16 VtV[48][72];
  __shared__ float  Pbuf[4][32][68];

  int bh = blockIdx.x; int b = bh >> 3, h = bh & 7;
  int t = threadIdx.x;
  int w = t >> 6, lane = t & 63;
  int l15 = lane & 15, g = lane >> 4;
  const float scale = 0.17677669529663687f;  // 32^-0.5

  int qrow0 = b * N_PTS + blockIdx.y * 128 + w * 32;
  bf16x8 aq[2];
#pragma unroll
  for (int mt = 0; mt < 2; ++mt)
    aq[mt] = *(const bf16x8*)&qb[(size_t)(qrow0 + mt * 16 + l15) * C_DIM +
                                 h * 32 + g * 8];

  float mrun[2][4], lrun[2][4];
  f32x4 accf[2][3];
#pragma unroll
  for (int mt = 0; mt < 2; ++mt)
#pragma unroll
    for (int r = 0; r < 4; ++r) { mrun[mt][r] = -1e30f; lrun[mt][r] = 0.f; }
#pragma unroll
  for (int mt = 0; mt < 2; ++mt)
#pragma unroll
    for (int nt = 0; nt < 3; ++nt) accf[mt][nt] = (f32x4){0.f, 0.f, 0.f, 0.f};

  int vdv = t % 48;
  int vkb = (t / 48) * 16;

  for (int kt = 0; kt < 16; ++kt) {
    int key0 = kt * 64;
    __syncthreads();
    // stage K tile: 64 keys x 32 d, one 16B copy per thread
    {
      int j = t >> 2, c16 = t & 3;
      *(uint4*)&KsV[j][c16 * 8] =
          *(const uint4*)&kvb[(size_t)(b * N_PTS + key0 + j) * 512 + h * 32 +
                              c16 * 8];
    }
    // stage V' transposed: 48 dv x 64 keys
    if (t < 192) {
#pragma unroll
      for (int kk = 0; kk < 16; ++kk) {
        size_t kr = (size_t)(b * N_PTS + key0 + vkb + kk);
        if (vdv < 32)
          VtV[vdv][vkb + kk] = kvb[kr * 512 + 256 + h * 32 + vdv];
        else
          VtV[vdv][vkb + kk] = (__bf16)ceb[kr * MDIM_N + h * 16 + vdv - 32];
      }
    }
    __syncthreads();

    // S = Q K^T (scale folded post-MFMA)
    float sv[2][4][4];
#pragma unroll
    for (int nt = 0; nt < 4; ++nt) {
      bf16x8 bk = *(const bf16x8*)&KsV[nt * 16 + l15][g * 8];
      f32x4 z = (f32x4){0.f, 0.f, 0.f, 0.f};
      f32x4 s0 = __builtin_amdgcn_mfma_f32_16x16x32_bf16(aq[0], bk, z, 0, 0, 0);
      f32x4 s1 = __builtin_amdgcn_mfma_f32_16x16x32_bf16(aq[1], bk, z, 0, 0, 0);
#pragma unroll
      for (int r = 0; r < 4; ++r) {
        sv[0][nt][r] = s0[r] * scale;
        sv[1][nt][r] = s1[r] * scale;
      }
    }

    // online softmax + P write
#pragma unroll
    for (int mt = 0; mt < 2; ++mt) {
#pragma unroll
      for (int r = 0; r < 4; ++r) {
        float tm = fmaxf(fmaxf(sv[mt][0][r], sv[mt][1][r]),
                         fmaxf(sv[mt][2][r], sv[mt][3][r]));
#pragma unroll
        for (int o = 1; o <= 8; o <<= 1) tm = fmaxf(tm, __shfl_xor(tm, o));
        float nm = fmaxf(mrun[mt][r], tm);
        float corr = __expf(mrun[mt][r] - nm);
        mrun[mt][r] = nm;
        float rs = 0.f;
#pragma unroll
        for (int nt = 0; nt < 4; ++nt) {
          float p = __expf(sv[mt][nt][r] - nm);
          sv[mt][nt][r] = p;
          rs += p;
        }
#pragma unroll
        for (int o = 1; o <= 8; o <<= 1) rs += __shfl_xor(rs, o);
        lrun[mt][r] = lrun[mt][r] * corr + rs;
#pragma unroll
        for (int nt = 0; nt < 3; ++nt) accf[mt][nt][r] *= corr;
        int prow = mt * 16 + g * 4 + r;
#pragma unroll
        for (int nt = 0; nt < 4; ++nt)
          Pbuf[w][prow][nt * 16 + l15] = sv[mt][nt][r];
      }
    }

    // reload P as A fragments (wave-internal)
    bf16x8 ap[2][2];
#pragma unroll
    for (int mt = 0; mt < 2; ++mt)
#pragma unroll
      for (int kc = 0; kc < 2; ++kc) {
        const float* pp = &Pbuf[w][mt * 16 + l15][kc * 32 + g * 8];
        float4 x0 = *(const float4*)pp;
        float4 x1 = *(const float4*)(pp + 4);
        bf16x8 a;
        a[0] = (__bf16)x0.x; a[1] = (__bf16)x0.y;
        a[2] = (__bf16)x0.z; a[3] = (__bf16)x0.w;
        a[4] = (__bf16)x1.x; a[5] = (__bf16)x1.y;
        a[6] = (__bf16)x1.z; a[7] = (__bf16)x1.w;
        ap[mt][kc] = a;
      }

    // PV
#pragma unroll
    for (int nt = 0; nt < 3; ++nt)
#pragma unroll
      for (int kc = 0; kc < 2; ++kc) {
        bf16x8 bv = *(const bf16x8*)&VtV[nt * 16 + l15][kc * 32 + g * 8];
        accf[0][nt] = __builtin_amdgcn_mfma_f32_16x16x32_bf16(
            ap[0][kc], bv, accf[0][nt], 0, 0, 0);
        accf[1][nt] = __builtin_amdgcn_mfma_f32_16x16x32_bf16(
            ap[1][kc], bv, accf[1][nt], 0, 0, 0);
      }
  }

  // epilogue: normalize; av bf16; dmc = cr - ce bf16
#pragma unroll
  for (int mt = 0; mt < 2; ++mt)
#pragma unroll
    for (int r = 0; r < 4; ++r) {
      float inv = 1.f / lrun[mt][r];
      int row = qrow0 + mt * 16 + g * 4 + r;
      av[(size_t)row * C_DIM + h * 32 + l15] = (__bf16)(accf[mt][0][r] * inv);
      av[(size_t)row * C_DIM + h * 32 + 16 + l15] =
          (__bf16)(accf[mt][1][r] * inv);
      size_t ci = (size_t)row * MDIM_N + h * 16 + l15;
      dmc[ci] = (__bf16)(accf[mt][2][r] * inv - ceb[ci]);
    }
}

// ---------------------------------------------------------------- MFMA GEMM
// out[r,m] = sum_k A[r,k] * W[m,k]; BM=128, BK=64, BN template {64,128}.
// 4 waves (2m x 2n), wave tile 64 x BN/2. XOR-swizzled LDS (c16 ^= row&7).
// MODE 0: out bf16 (q)            MODE 1: A batch-swapped, out bf16 (kv)
// MODE 2: out f32 = e0+acc+bias (proj->xn2)
// MODE 3: out f32 = acc+bias (motion; A pre-diffed)
// MODE 4: dw+PReLU epilogue, out bf16 (fc1)
// MODE 5: transposed float4 residual store (fc2)
template <int MODE, int BNt>
__global__ __launch_bounds__(256)
void mgemm_k(const __bf16* __restrict__ A, const __bf16* __restrict__ W,
             const float* __restrict__ bias, void* __restrict__ outp,
             const float* __restrict__ e0, const float* __restrict__ e2,
             const float* __restrict__ e3, const float* __restrict__ pre,
             int K, int M) {
  constexpr int WN = BNt / 2;
  constexpr int NR = WN / 16;
  __shared__ __bf16 Al[128 * 64];
  __shared__ __bf16 Bl[BNt * 64];
  int t = threadIdx.x;
  int w = t >> 6, lane = t & 63;
  int l15 = lane & 15, g = lane >> 4;
  int wr = w >> 1, wn = w & 1;
  int r0 = blockIdx.y * 128;
  int m0 = blockIdx.x * BNt;

  f32x4 acc[4][NR];
#pragma unroll
  for (int i = 0; i < 4; ++i)
#pragma unroll
    for (int j = 0; j < NR; ++j) acc[i][j] = (f32x4){0.f, 0.f, 0.f, 0.f};

  for (int kt = 0; kt < K; kt += 64) {
    __syncthreads();
    // stage A 128x64 (4 passes of 256 x 16B)
#pragma unroll
    for (int p = 0; p < 4; ++p) {
      int flat = p * 256 + t;
      int row = flat >> 3, c16 = flat & 7;
      int gr = r0 + row;
      if (MODE == 1) {
        int b = gr >> 10;
        gr = (((b + 4) & 7) << 10) | (gr & 1023);
      }
      *(uint4*)&Al[row * 64 + (c16 ^ (row & 7)) * 8] =
          *(const uint4*)&A[(size_t)gr * K + kt + c16 * 8];
    }
    // stage B BNt x 64
#pragma unroll
    for (int p = 0; p < BNt / 32; ++p) {
      int flat = p * 256 + t;
      int row = flat >> 3, c16 = flat & 7;
      *(uint4*)&Bl[row * 64 + (c16 ^ (row & 7)) * 8] =
          *(const uint4*)&W[(size_t)(m0 + row) * K + kt + c16 * 8];
    }
    __syncthreads();
#pragma unroll
    for (int ks = 0; ks < 2; ++ks) {
      bf16x8 af[4], bf_[NR];
#pragma unroll
      for (int mf = 0; mf < 4; ++mf) {
        int row = wr * 64 + mf * 16 + l15;
        af[mf] = *(const bf16x8*)&Al[row * 64 + ((ks * 4 + g) ^ (l15 & 7)) * 8];
      }
#pragma unroll
      for (int nf = 0; nf < NR; ++nf) {
        int row = wn * WN + nf * 16 + l15;
        bf_[nf] = *(const bf16x8*)&Bl[row * 64 + ((ks * 4 + g) ^ (l15 & 7)) * 8];
      }
#pragma unroll
      for (int mf = 0; mf < 4; ++mf)
#pragma unroll
        for (int nf = 0; nf < NR; ++nf)
          acc[mf][nf] = __builtin_amdgcn_mfma_f32_16x16x32_bf16(
              af[mf], bf_[nf], acc[mf][nf], 0, 0, 0);
    }
  }

  float a_pre = (MODE == 4) ? pre[0] : 0.f;
#pragma unroll
  for (int mf = 0; mf < 4; ++mf) {
#pragma unroll
    for (int nf = 0; nf < NR; ++nf) {
      int m = m0 + wn * WN + nf * 16 + l15;
      int rbase = r0 + wr * 64 + mf * 16 + g * 4;
      if (MODE == 5) {
        int b = rbase >> 10, n = rbase & 1023;
        size_t oi = (size_t)b * CN + (size_t)m * N_PTS + n;
        float4 xv = *(const float4*)&e0[oi];
        float bs = bias[m];
        float4 ov;
        ov.x = xv.x + acc[mf][nf][0] + bs;
        ov.y = xv.y + acc[mf][nf][1] + bs;
        ov.z = xv.z + acc[mf][nf][2] + bs;
        ov.w = xv.w + acc[mf][nf][3] + bs;
        *(float4*)&((float*)outp)[oi] = ov;
      } else {
#pragma unroll
        for (int r = 0; r < 4; ++r) {
          size_t oi = (size_t)(rbase + r) * M + m;
          float v = acc[mf][nf][r];
          if (MODE == 0 || MODE == 1) {
            ((__bf16*)outp)[oi] = (__bf16)v;
          } else if (MODE == 2) {
            ((float*)outp)[oi] = e0[oi] + v + bias[m];
          } else if (MODE == 3) {
            ((float*)outp)[oi] = v + bias[m];
          } else if (MODE == 4) {
            v += bias[m];
            v = v * e2[m] + e3[m];
            ((__bf16*)outp)[oi] = (__bf16)(v >= 0.f ? v : a_pre * v);
          }
        }
      }
    }
  }
}

// ---------------------------------------------------------------- BN2
__global__ __launch_bounds__(256)
void bn2_stats_k(const float* __restrict__ xn2, float* __restrict__ raw) {
  int t = threadIdx.x;
  float s = 0.f, q = 0.f;
  int r0 = blockIdx.x * 128;
  for (int i = 0; i < 128; ++i) {
    float v = xn2[(size_t)(r0 + i) * C_DIM + t];
    s += v; q += v * v;
  }
  atomicAdd(&raw[t], s);
  atomicAdd(&raw[C_DIM + t], q);
}

__global__ __launch_bounds__(256)
void bn2_final_k(const float* __restrict__ raw, const float* __restrict__ g,
                 const float* __restrict__ bb, float* __restrict__ st) {
  int c = threadIdx.x;
  float mean = raw[c] * (1.f / 8192.f);
  float var  = raw[C_DIM + c] * (1.f / 8192.f) - mean * mean;
  float sc   = g[c] * rsqrtf(var + EPSV);
  st[c]         = sc;
  st[C_DIM + c] = bb[c] - mean * sc;
}

// xb = bf16(bn2(xn2))
__global__ __launch_bounds__(256)
void bn2_apply_k(const float* __restrict__ xn2, const float* __restrict__ st,
                 __bf16* __restrict__ xb) {
  int i = blockIdx.x * 256 + threadIdx.x;   // float4 index, 524288 total
  float4 v = ((const float4*)xn2)[i];
  int c = (i * 4) & 255;
  ushort4 u;
  u.x = bfu(v.x * st[c]     + st[C_DIM + c]);
  u.y = bfu(v.y * st[c + 1] + st[C_DIM + c + 1]);
  u.z = bfu(v.z * st[c + 2] + st[C_DIM + c + 2]);
  u.w = bfu(v.w * st[c + 3] + st[C_DIM + c + 3]);
  ((ushort4*)xb)[i] = u;
}

extern "C" void kernel_launch(void* const* d_in, const int* in_sizes, int n_in,
                              void* d_out, int out_size, void* d_ws,
                              size_t ws_size, hipStream_t stream) {
  const float* x       = (const float*)d_in[0];
  const float* cor     = (const float*)d_in[1];
  const float* q_w     = (const float*)d_in[2];
  const float* kv_w    = (const float*)d_in[3];
  const float* cor_w   = (const float*)d_in[4];
  const float* proj_w  = (const float*)d_in[5];
  const float* proj_b  = (const float*)d_in[6];
  const float* mproj_w = (const float*)d_in[7];
  const float* mproj_b = (const float*)d_in[8];
  const float* g1      = (const float*)d_in[9];
  const float* b1      = (const float*)d_in[10];
  const float* g2      = (const float*)d_in[11];
  const float* b2      = (const float*)d_in[12];
  const float* fc1_w   = (const float*)d_in[13];
  const float* fc1_b   = (const float*)d_in[14];
  const float* dw_w    = (const float*)d_in[15];
  const float* dw_b    = (const float*)d_in[16];
  const float* prelu   = (const float*)d_in[17];
  const float* fc2_w   = (const float*)d_in[18];
  const float* fc2_b   = (const float*)d_in[19];

  char* base = (char*)d_ws;
  const size_t MB = 1u << 20;
  float*  xn32 = (float*)(base + 0);            // 8 MB
  __bf16* xnb  = (__bf16*)(base + 8 * MB);      // 4 MB
  __bf16* qb   = (__bf16*)(base + 12 * MB);     // 4 MB
  __bf16* kvb  = (__bf16*)(base + 16 * MB);     // 8 MB
  float*  ceb  = (float*)(base + 24 * MB);      // 4 MB
  __bf16* av   = (__bf16*)(base + 28 * MB);     // 4 MB
  __bf16* dmc  = (__bf16*)(base + 30 * MB);     // 2 MB
  float*  xn2  = (float*)(base + 32 * MB);      // 8 MB
  __bf16* xb   = (__bf16*)(base + 40 * MB);     // 4 MB
  __bf16* qwb  = (__bf16*)(base + 44 * MB);           // 128 KB
  __bf16* kvwb = (__bf16*)(base + 44 * MB + 131072);  // 256 KB
  __bf16* pwb  = (__bf16*)(base + 44 * MB + 393216);  // 128 KB
  __bf16* mwb  = (__bf16*)(base + 44 * MB + 524288);  // 32 KB
  __bf16* f1wb = (__bf16*)(base + 44 * MB + 557056);  // 512 KB
  __bf16* f2wb = (__bf16*)(base + 44 * MB + 1081344); // 512 KB
  float*  st1  = (float*)(base + 46 * MB);
  float*  raw2 = (float*)(base + 46 * MB + 4096);
  float*  st2  = (float*)(base + 46 * MB + 8192);
  __bf16* hb   = (__bf16*)(base + 12 * MB);     // 16 MB overlay (qb/kvb/ceb dead)
  float* out0 = (float*)d_out;
  float* out1 = out0 + 2097152;

  hipMemsetAsync(raw2, 0, 512 * sizeof(float), stream);

  wcvt_k<<<784, 256, 0, stream>>>(q_w, kv_w, proj_w, mproj_w, fc1_w, fc2_w,
                                  qwb, kvwb, pwb, mwb, f1wb, f2wb);
  bn1_stats_k<<<256, 256, 0, stream>>>(x, g1, b1, st1);
  norm1_t_k<<<dim3(8, 32, 8), dim3(32, 8), 0, stream>>>(x, st1, xn32, xnb);

  // q = xn @ q_w^T (bf16 out)
  mgemm_k<0, 64><<<dim3(4, 64), 256, 0, stream>>>(
      xnb, qwb, nullptr, qb, nullptr, nullptr, nullptr, nullptr, 256, 256);
  // kv = xr @ kv_w^T (bf16 out, batch-swapped A)
  mgemm_k<1, 128><<<dim3(4, 64), 256, 0, stream>>>(
      xnb, kvwb, nullptr, kvb, nullptr, nullptr, nullptr, nullptr, 256, 512);
  ce_k<<<4096, 256, 0, stream>>>(cor, cor_w, ceb);

  attn_k<<<dim3(64, 8), 256, 0, stream>>>(qb, kvb, ceb, av, dmc);

  // xn2 = xn + av @ proj_w^T + proj_b (f32)
  mgemm_k<2, 64><<<dim3(4, 64), 256, 0, stream>>>(
      av, pwb, proj_b, xn2, xn32, nullptr, nullptr, nullptr, 256, 256);
  // motion = dmc @ mproj_w^T + mproj_b (f32, direct to out1)
  mgemm_k<3, 64><<<dim3(2, 64), 256, 0, stream>>>(
      dmc, mwb, mproj_b, out1, nullptr, nullptr, nullptr, nullptr, 128, 128);

  bn2_stats_k<<<64, 256, 0, stream>>>(xn2, raw2);
  bn2_final_k<<<1, 256, 0, stream>>>(raw2, g2, b2, st2);
  bn2_apply_k<<<2048, 256, 0, stream>>>(xn2, st2, xb);

  // h = prelu(dw(xb @ fc1_w^T + fc1_b)) (bf16 out)
  mgemm_k<4, 128><<<dim3(8, 64), 256, 0, stream>>>(
      xb, f1wb, fc1_b, hb, nullptr, dw_w, dw_b, prelu, 256, HID_N);
  // x_out = x + (h @ fc2_w^T + fc2_b)^T (f32, transposed float4 store)
  mgemm_k<5, 64><<<dim3(4, 64), 256, 0, stream>>>(
      hb, f2wb, fc2_b, out0, x, nullptr, nullptr, nullptr, HID_N, 256);
}

// Round 4
// 156.019 us; speedup vs baseline: 5.5694x; 1.8017x over previous
//
#include <hip/hip_runtime.h>
#include <hip/hip_bf16.h>
#include <math.h>

// MotionFormerBlock: bf16 MFMA GEMMs + bf16 MFMA flash attention (Vt-precomp).
// Shapes fixed: B=8, N=1024, C=DIM=256, MDIM=128, H=8, HD=32, MHD=16, HID=1024.
#define C_DIM 256
#define N_PTS 1024
#define H_N 8
#define MDIM_N 128
#define HID_N 1024
#define EPSV 1e-5f
#define R_TOT 8192
#define CN 262144               // C_DIM * N_PTS

typedef __bf16 bf16x8 __attribute__((ext_vector_type(8)));
typedef float f32x4 __attribute__((ext_vector_type(4)));

__device__ inline unsigned short bfu(float f) {
  union { __bf16 h; unsigned short u; } c;
  c.h = (__bf16)f;
  return c.u;
}

// ---------------------------------------------------------------- weight cvt
__global__ __launch_bounds__(256)
void wcvt_k(const float* __restrict__ s0, const float* __restrict__ s1,
            const float* __restrict__ s2, const float* __restrict__ s3,
            const float* __restrict__ s4, const float* __restrict__ s5,
            __bf16* d0, __bf16* d1, __bf16* d2, __bf16* d3, __bf16* d4,
            __bf16* d5) {
  int i = blockIdx.x * 256 + threadIdx.x;
  const float* s; __bf16* d; int off;
  if      (i <  16384) { s = s0; d = d0; off = 0; }
  else if (i <  49152) { s = s1; d = d1; off = 16384; }
  else if (i <  65536) { s = s2; d = d2; off = 49152; }
  else if (i <  69632) { s = s3; d = d3; off = 65536; }
  else if (i < 135168) { s = s4; d = d4; off = 69632; }
  else                 { s = s5; d = d5; off = 135168; }
  int j = i - off;
  float4 v = ((const float4*)s)[j];
  ushort4 u;
  u.x = bfu(v.x); u.y = bfu(v.y); u.z = bfu(v.z); u.w = bfu(v.w);
  ((ushort4*)d)[j] = u;
}

// ---------------------------------------------------------------- BN1 stats
__global__ __launch_bounds__(256)
void bn1_stats_k(const float* __restrict__ x, const float* __restrict__ g,
                 const float* __restrict__ bb, float* __restrict__ st) {
  int c = blockIdx.x;
  int t = threadIdx.x;
  float s = 0.f, q = 0.f;
  for (int i = 0; i < 32; ++i) {
    int idx = t + i * 256;
    int b = idx >> 10, n = idx & 1023;
    float v = x[(size_t)b * CN + (size_t)c * N_PTS + n];
    s += v; q += v * v;
  }
  __shared__ float ss[256], sq[256];
  ss[t] = s; sq[t] = q;
  __syncthreads();
  for (int off = 128; off > 0; off >>= 1) {
    if (t < off) { ss[t] += ss[t + off]; sq[t] += sq[t + off]; }
    __syncthreads();
  }
  if (t == 0) {
    float mean = ss[0] * (1.f / 8192.f);
    float var  = sq[0] * (1.f / 8192.f) - mean * mean;
    float sc   = g[c] * rsqrtf(var + EPSV);
    st[c]          = sc;
    st[C_DIM + c]  = bb[c] - mean * sc;
  }
}

// ------------------------------------------- normalize + transpose to tokens
__global__ __launch_bounds__(256)
void norm1_t_k(const float* __restrict__ x, const float* __restrict__ st,
               float* __restrict__ xn, __bf16* __restrict__ xnb) {
  __shared__ float tile[32][33];
  int c0 = blockIdx.x * 32, n0 = blockIdx.y * 32, b = blockIdx.z;
  int tx = threadIdx.x, ty = threadIdx.y;
#pragma unroll
  for (int k = 0; k < 4; ++k) {
    int ci = ty + k * 8;
    int c = c0 + ci;
    float v = x[(size_t)b * CN + (size_t)c * N_PTS + n0 + tx];
    tile[ci][tx] = v * st[c] + st[C_DIM + c];
  }
  __syncthreads();
#pragma unroll
  for (int k = 0; k < 4; ++k) {
    int ni = ty + k * 8;
    size_t o = ((size_t)(b * N_PTS + n0 + ni)) * C_DIM + c0 + tx;
    float v = tile[tx][ni];
    xn[o] = v;
    xnb[o] = (__bf16)v;
  }
}

// ---------------------------------------------------------------- ce = cor @ cor_w^T
// row-major f32 (used by attn dmc epilogue)
__global__ __launch_bounds__(256)
void ce_k(const float* __restrict__ cor, const float* __restrict__ cw,
          float* __restrict__ ce) {
  int t = threadIdx.x;
  int r = blockIdx.x * 2 + (t >> 7);
  int j = t & 127;
  float c0 = cor[r * 3 + 0], c1 = cor[r * 3 + 1], c2 = cor[r * 3 + 2];
  ce[(size_t)r * MDIM_N + j] =
      c0 * cw[j * 3 + 0] + c1 * cw[j * 3 + 1] + c2 * cw[j * 3 + 2];
}

// --------------------------------------- ceh transposed into vt rows 32..47
// vt[bh][32+md][n] = bf16(cor[b,n,:] . cw[h*16+md,:]); computed from cor.
__global__ __launch_bounds__(256)
void cet_k(const float* __restrict__ cor, const float* __restrict__ cw,
           __bf16* __restrict__ vt) {
  __shared__ float cs[768];           // 256 tokens x 3
  int bh = blockIdx.x; int b = bh >> 3, h = bh & 7;
  int n0 = blockIdx.y * 256;
  int t = threadIdx.x;
  for (int i = t; i < 768; i += 256)
    cs[i] = cor[(size_t)(b * N_PTS + n0) * 3 + i];
  __syncthreads();
  int md = t >> 4, ns = (t & 15) * 16;
  float w0 = cw[(h * 16 + md) * 3 + 0];
  float w1 = cw[(h * 16 + md) * 3 + 1];
  float w2 = cw[(h * 16 + md) * 3 + 2];
  __bf16* dst = &vt[((size_t)bh * 48 + 32 + md) * 1024 + n0 + ns];
#pragma unroll
  for (int g2 = 0; g2 < 4; ++g2) {
    ushort4 u;
    float v0 = cs[(ns + g2 * 4 + 0) * 3] * w0 + cs[(ns + g2 * 4 + 0) * 3 + 1] * w1 + cs[(ns + g2 * 4 + 0) * 3 + 2] * w2;
    float v1 = cs[(ns + g2 * 4 + 1) * 3] * w0 + cs[(ns + g2 * 4 + 1) * 3 + 1] * w1 + cs[(ns + g2 * 4 + 1) * 3 + 2] * w2;
    float v2 = cs[(ns + g2 * 4 + 2) * 3] * w0 + cs[(ns + g2 * 4 + 2) * 3 + 1] * w1 + cs[(ns + g2 * 4 + 2) * 3 + 2] * w2;
    float v3 = cs[(ns + g2 * 4 + 3) * 3] * w0 + cs[(ns + g2 * 4 + 3) * 3 + 1] * w1 + cs[(ns + g2 * 4 + 3) * 3 + 2] * w2;
    u.x = bfu(v0); u.y = bfu(v1); u.z = bfu(v2); u.w = bfu(v3);
    *(ushort4*)&dst[g2 * 4] = u;
  }
}

// ---------------------------------------------------------------- MFMA attention
// 4 waves/block, one (b,h); wave owns 32 q-rows. K from kb (row-major),
// V' from vt (pre-transposed [bh][48][1024]). Coalesced uint4 staging.
__global__ __launch_bounds__(256)
void attn_k(const __bf16* __restrict__ qb, const __bf16* __restrict__ kb,
            const __bf16* __restrict__ vt, const float* __restrict__ ceb,
            __bf16* __restrict__ av, __bf16* __restrict__ dmc) {
  __shared__ __bf16 KsV[64][40];
  __shared__ __bf16 VtV[48][72];
  __shared__ float  Pbuf[4][32][68];

  int bh = blockIdx.x; int b = bh >> 3, h = bh & 7;
  int t = threadIdx.x;
  int w = t >> 6, lane = t & 63;
  int l15 = lane & 15, g = lane >> 4;

  int qrow0 = b * N_PTS + blockIdx.y * 128 + w * 32;
  bf16x8 aq[2];
#pragma unroll
  for (int mt = 0; mt < 2; ++mt)
    aq[mt] = *(const bf16x8*)&qb[(size_t)(qrow0 + mt * 16 + l15) * C_DIM +
                                 h * 32 + g * 8];

  float mrun[2][4], lrun[2][4];
  f32x4 accf[2][3];
#pragma unroll
  for (int mt = 0; mt < 2; ++mt)
#pragma unroll
    for (int r = 0; r < 4; ++r) { mrun[mt][r] = -1e30f; lrun[mt][r] = 0.f; }
#pragma unroll
  for (int mt = 0; mt < 2; ++mt)
#pragma unroll
    for (int nt = 0; nt < 3; ++nt) accf[mt][nt] = (f32x4){0.f, 0.f, 0.f, 0.f};

  for (int kt = 0; kt < 16; ++kt) {
    int key0 = kt * 64;
    __syncthreads();
    // stage K tile: 64 keys x 32 d, one uint4 per thread (coalesced)
    {
      int j = t >> 2, c16 = t & 3;
      *(uint4*)&KsV[j][c16 * 8] =
          *(const uint4*)&kb[(size_t)(b * N_PTS + key0 + j) * 256 + h * 32 +
                             c16 * 8];
    }
    // stage V' tile: 48 dv x 64 keys from pre-transposed vt (coalesced)
    {
      int dv = t >> 3, kg = t & 7;
      *(uint4*)&VtV[dv][kg * 8] =
          *(const uint4*)&vt[((size_t)bh * 48 + dv) * 1024 + key0 + kg * 8];
      if (t < 128) {
        int task = 256 + t;
        int dv2 = task >> 3, kg2 = task & 7;
        *(uint4*)&VtV[dv2][kg2 * 8] =
            *(const uint4*)&vt[((size_t)bh * 48 + dv2) * 1024 + key0 + kg2 * 8];
      }
    }
    __syncthreads();

    // S = Q K^T (scale pre-folded into qb)
    float sv[2][4][4];
#pragma unroll
    for (int nt = 0; nt < 4; ++nt) {
      bf16x8 bk = *(const bf16x8*)&KsV[nt * 16 + l15][g * 8];
      f32x4 z = (f32x4){0.f, 0.f, 0.f, 0.f};
      f32x4 s0 = __builtin_amdgcn_mfma_f32_16x16x32_bf16(aq[0], bk, z, 0, 0, 0);
      f32x4 s1 = __builtin_amdgcn_mfma_f32_16x16x32_bf16(aq[1], bk, z, 0, 0, 0);
#pragma unroll
      for (int r = 0; r < 4; ++r) { sv[0][nt][r] = s0[r]; sv[1][nt][r] = s1[r]; }
    }

    // online softmax + P write
#pragma unroll
    for (int mt = 0; mt < 2; ++mt) {
#pragma unroll
      for (int r = 0; r < 4; ++r) {
        float tm = fmaxf(fmaxf(sv[mt][0][r], sv[mt][1][r]),
                         fmaxf(sv[mt][2][r], sv[mt][3][r]));
#pragma unroll
        for (int o = 1; o <= 8; o <<= 1) tm = fmaxf(tm, __shfl_xor(tm, o));
        float nm = fmaxf(mrun[mt][r], tm);
        float corr = __expf(mrun[mt][r] - nm);
        mrun[mt][r] = nm;
        float rs = 0.f;
#pragma unroll
        for (int nt = 0; nt < 4; ++nt) {
          float p = __expf(sv[mt][nt][r] - nm);
          sv[mt][nt][r] = p;
          rs += p;
        }
#pragma unroll
        for (int o = 1; o <= 8; o <<= 1) rs += __shfl_xor(rs, o);
        lrun[mt][r] = lrun[mt][r] * corr + rs;
#pragma unroll
        for (int nt = 0; nt < 3; ++nt) accf[mt][nt][r] *= corr;
        int prow = mt * 16 + g * 4 + r;
#pragma unroll
        for (int nt = 0; nt < 4; ++nt)
          Pbuf[w][prow][nt * 16 + l15] = sv[mt][nt][r];
      }
    }

    // reload P as A fragments (wave-internal)
    bf16x8 ap[2][2];
#pragma unroll
    for (int mt = 0; mt < 2; ++mt)
#pragma unroll
      for (int kc = 0; kc < 2; ++kc) {
        const float* pp = &Pbuf[w][mt * 16 + l15][kc * 32 + g * 8];
        float4 x0 = *(const float4*)pp;
        float4 x1 = *(const float4*)(pp + 4);
        bf16x8 a;
        a[0] = (__bf16)x0.x; a[1] = (__bf16)x0.y;
        a[2] = (__bf16)x0.z; a[3] = (__bf16)x0.w;
        a[4] = (__bf16)x1.x; a[5] = (__bf16)x1.y;
        a[6] = (__bf16)x1.z; a[7] = (__bf16)x1.w;
        ap[mt][kc] = a;
      }

    // PV
#pragma unroll
    for (int nt = 0; nt < 3; ++nt)
#pragma unroll
      for (int kc = 0; kc < 2; ++kc) {
        bf16x8 bv = *(const bf16x8*)&VtV[nt * 16 + l15][kc * 32 + g * 8];
        accf[0][nt] = __builtin_amdgcn_mfma_f32_16x16x32_bf16(
            ap[0][kc], bv, accf[0][nt], 0, 0, 0);
        accf[1][nt] = __builtin_amdgcn_mfma_f32_16x16x32_bf16(
            ap[1][kc], bv, accf[1][nt], 0, 0, 0);
      }
  }

  // epilogue
#pragma unroll
  for (int mt = 0; mt < 2; ++mt)
#pragma unroll
    for (int r = 0; r < 4; ++r) {
      float inv = 1.f / lrun[mt][r];
      int row = qrow0 + mt * 16 + g * 4 + r;
      av[(size_t)row * C_DIM + h * 32 + l15] = (__bf16)(accf[mt][0][r] * inv);
      av[(size_t)row * C_DIM + h * 32 + 16 + l15] =
          (__bf16)(accf[mt][1][r] * inv);
      size_t ci = (size_t)row * MDIM_N + h * 16 + l15;
      dmc[ci] = (__bf16)(accf[mt][2][r] * inv - ceb[ci]);
    }
}

// ---------------------------------------------------------------- MFMA GEMM
// MODE 0: out bf16 * softmax-scale (q)
// MODE 1: A batch-swapped; m<256 -> kb row-major bf16; m>=256 -> vt transposed
// MODE 2: out f32 = e0+acc+bias (proj->xn2)
// MODE 3: out f32 = acc+bias (motion)
// MODE 4: dw+PReLU epilogue, out bf16 (fc1)
// MODE 5: transposed float4 residual store (fc2)
template <int MODE, int BNt>
__global__ __launch_bounds__(256)
void mgemm_k(const __bf16* __restrict__ A, const __bf16* __restrict__ W,
             const float* __restrict__ bias, void* __restrict__ outp,
             const float* __restrict__ e0, const float* __restrict__ e2,
             const float* __restrict__ e3, const float* __restrict__ pre,
             __bf16* __restrict__ vtp, int K, int M) {
  constexpr int WN = BNt / 2;
  constexpr int NR = WN / 16;
  __shared__ __bf16 Al[128 * 64];
  __shared__ __bf16 Bl[BNt * 64];
  int t = threadIdx.x;
  int w = t >> 6, lane = t & 63;
  int l15 = lane & 15, g = lane >> 4;
  int wr = w >> 1, wn = w & 1;
  int r0 = blockIdx.y * 128;
  int m0 = blockIdx.x * BNt;

  f32x4 acc[4][NR];
#pragma unroll
  for (int i = 0; i < 4; ++i)
#pragma unroll
    for (int j = 0; j < NR; ++j) acc[i][j] = (f32x4){0.f, 0.f, 0.f, 0.f};

  for (int kt = 0; kt < K; kt += 64) {
    __syncthreads();
#pragma unroll
    for (int p = 0; p < 4; ++p) {
      int flat = p * 256 + t;
      int row = flat >> 3, c16 = flat & 7;
      int gr = r0 + row;
      if (MODE == 1) {
        int b = gr >> 10;
        gr = (((b + 4) & 7) << 10) | (gr & 1023);
      }
      *(uint4*)&Al[row * 64 + (c16 ^ (row & 7)) * 8] =
          *(const uint4*)&A[(size_t)gr * K + kt + c16 * 8];
    }
#pragma unroll
    for (int p = 0; p < BNt / 32; ++p) {
      int flat = p * 256 + t;
      int row = flat >> 3, c16 = flat & 7;
      *(uint4*)&Bl[row * 64 + (c16 ^ (row & 7)) * 8] =
          *(const uint4*)&W[(size_t)(m0 + row) * K + kt + c16 * 8];
    }
    __syncthreads();
#pragma unroll
    for (int ks = 0; ks < 2; ++ks) {
      bf16x8 af[4], bf_[NR];
#pragma unroll
      for (int mf = 0; mf < 4; ++mf) {
        int row = wr * 64 + mf * 16 + l15;
        af[mf] = *(const bf16x8*)&Al[row * 64 + ((ks * 4 + g) ^ (l15 & 7)) * 8];
      }
#pragma unroll
      for (int nf = 0; nf < NR; ++nf) {
        int row = wn * WN + nf * 16 + l15;
        bf_[nf] = *(const bf16x8*)&Bl[row * 64 + ((ks * 4 + g) ^ (l15 & 7)) * 8];
      }
#pragma unroll
      for (int mf = 0; mf < 4; ++mf)
#pragma unroll
        for (int nf = 0; nf < NR; ++nf)
          acc[mf][nf] = __builtin_amdgcn_mfma_f32_16x16x32_bf16(
              af[mf], bf_[nf], acc[mf][nf], 0, 0, 0);
    }
  }

  float a_pre = (MODE == 4) ? pre[0] : 0.f;
#pragma unroll
  for (int mf = 0; mf < 4; ++mf) {
#pragma unroll
    for (int nf = 0; nf < NR; ++nf) {
      int m = m0 + wn * WN + nf * 16 + l15;
      int rbase = r0 + wr * 64 + mf * 16 + g * 4;
      if (MODE == 5) {
        int b = rbase >> 10, n = rbase & 1023;
        size_t oi = (size_t)b * CN + (size_t)m * N_PTS + n;
        float4 xv = *(const float4*)&e0[oi];
        float bs = bias[m];
        float4 ov;
        ov.x = xv.x + acc[mf][nf][0] + bs;
        ov.y = xv.y + acc[mf][nf][1] + bs;
        ov.z = xv.z + acc[mf][nf][2] + bs;
        ov.w = xv.w + acc[mf][nf][3] + bs;
        *(float4*)&((float*)outp)[oi] = ov;
      } else if (MODE == 1 && m >= 256) {
        // V half -> vt transposed [bh][48][1024], 4 tokens packed
        int d = m - 256, hh = d >> 5, dd = d & 31;
        int b = rbase >> 10, n0v = rbase & 1023;
        ushort4 u;
        u.x = bfu(acc[mf][nf][0]); u.y = bfu(acc[mf][nf][1]);
        u.z = bfu(acc[mf][nf][2]); u.w = bfu(acc[mf][nf][3]);
        *(ushort4*)&vtp[(((size_t)b * 8 + hh) * 48 + dd) * 1024 + n0v] = u;
      } else {
#pragma unroll
        for (int r = 0; r < 4; ++r) {
          float v = acc[mf][nf][r];
          if (MODE == 0) {
            ((__bf16*)outp)[(size_t)(rbase + r) * M + m] =
                (__bf16)(v * 0.17677669529663687f);
          } else if (MODE == 1) {       // K half, row-major 256-stride
            ((__bf16*)outp)[(size_t)(rbase + r) * 256 + m] = (__bf16)v;
          } else if (MODE == 2) {
            size_t oi = (size_t)(rbase + r) * M + m;
            ((float*)outp)[oi] = e0[oi] + v + bias[m];
          } else if (MODE == 3) {
            ((float*)outp)[(size_t)(rbase + r) * M + m] = v + bias[m];
          } else if (MODE == 4) {
            v += bias[m];
            v = v * e2[m] + e3[m];
            ((__bf16*)outp)[(size_t)(rbase + r) * M + m] =
                (__bf16)(v >= 0.f ? v : a_pre * v);
          }
        }
      }
    }
  }
}

// ---------------------------------------------------------------- BN2
__global__ __launch_bounds__(256)
void bn2_stats_k(const float* __restrict__ xn2, float* __restrict__ raw) {
  int t = threadIdx.x;
  float s = 0.f, q = 0.f;
  int r0 = blockIdx.x * 128;
  for (int i = 0; i < 128; ++i) {
    float v = xn2[(size_t)(r0 + i) * C_DIM + t];
    s += v; q += v * v;
  }
  atomicAdd(&raw[t], s);
  atomicAdd(&raw[C_DIM + t], q);
}

__global__ __launch_bounds__(256)
void bn2_final_k(const float* __restrict__ raw, const float* __restrict__ g,
                 const float* __restrict__ bb, float* __restrict__ st) {
  int c = threadIdx.x;
  float mean = raw[c] * (1.f / 8192.f);
  float var  = raw[C_DIM + c] * (1.f / 8192.f) - mean * mean;
  float sc   = g[c] * rsqrtf(var + EPSV);
  st[c]         = sc;
  st[C_DIM + c] = bb[c] - mean * sc;
}

__global__ __launch_bounds__(256)
void bn2_apply_k(const float* __restrict__ xn2, const float* __restrict__ st,
                 __bf16* __restrict__ xb) {
  int i = blockIdx.x * 256 + threadIdx.x;
  float4 v = ((const float4*)xn2)[i];
  int c = (i * 4) & 255;
  ushort4 u;
  u.x = bfu(v.x * st[c]     + st[C_DIM + c]);
  u.y = bfu(v.y * st[c + 1] + st[C_DIM + c + 1]);
  u.z = bfu(v.z * st[c + 2] + st[C_DIM + c + 2]);
  u.w = bfu(v.w * st[c + 3] + st[C_DIM + c + 3]);
  ((ushort4*)xb)[i] = u;
}

extern "C" void kernel_launch(void* const* d_in, const int* in_sizes, int n_in,
                              void* d_out, int out_size, void* d_ws,
                              size_t ws_size, hipStream_t stream) {
  const float* x       = (const float*)d_in[0];
  const float* cor     = (const float*)d_in[1];
  const float* q_w     = (const float*)d_in[2];
  const float* kv_w    = (const float*)d_in[3];
  const float* cor_w   = (const float*)d_in[4];
  const float* proj_w  = (const float*)d_in[5];
  const float* proj_b  = (const float*)d_in[6];
  const float* mproj_w = (const float*)d_in[7];
  const float* mproj_b = (const float*)d_in[8];
  const float* g1      = (const float*)d_in[9];
  const float* b1      = (const float*)d_in[10];
  const float* g2      = (const float*)d_in[11];
  const float* b2      = (const float*)d_in[12];
  const float* fc1_w   = (const float*)d_in[13];
  const float* fc1_b   = (const float*)d_in[14];
  const float* dw_w    = (const float*)d_in[15];
  const float* dw_b    = (const float*)d_in[16];
  const float* prelu   = (const float*)d_in[17];
  const float* fc2_w   = (const float*)d_in[18];
  const float* fc2_b   = (const float*)d_in[19];

  char* base = (char*)d_ws;
  const size_t MB = 1u << 20;
  float*  xn32 = (float*)(base + 0);             // 0-8 MB  f32
  __bf16* xnb  = (__bf16*)(base + 8 * MB);       // 8-12
  __bf16* qb   = (__bf16*)(base + 12 * MB);      // 12-16
  __bf16* kb   = (__bf16*)(base + 16 * MB);      // 16-20
  __bf16* vt   = (__bf16*)(base + 20 * MB);      // 20-26 (64*48*1024 bf16)
  float*  ceb  = (float*)(base + 26 * MB);       // 26-30 f32
  __bf16* av   = (__bf16*)(base + 30 * MB);      // 30-34
  __bf16* dmc  = (__bf16*)(base + 34 * MB);      // 34-36
  float*  xn2  = (float*)(base + 36 * MB);       // 36-44 f32
  __bf16* xb   = (__bf16*)(base + 8 * MB);       // overlay xnb (dead post-kv)
  __bf16* hb   = (__bf16*)(base + 12 * MB);      // overlay 12-28 (fc1 out)
  __bf16* qwb  = (__bf16*)(base + 44 * MB);
  __bf16* kvwb = (__bf16*)(base + 44 * MB + 131072);
  __bf16* pwb  = (__bf16*)(base + 44 * MB + 393216);
  __bf16* mwb  = (__bf16*)(base + 44 * MB + 524288);
  __bf16* f1wb = (__bf16*)(base + 44 * MB + 557056);
  __bf16* f2wb = (__bf16*)(base + 44 * MB + 1081344);
  float*  st1  = (float*)(base + 45 * MB + 655360);
  float*  raw2 = st1 + 1024;
  float*  st2  = st1 + 2048;
  float* out0 = (float*)d_out;
  float* out1 = out0 + 2097152;

  hipMemsetAsync(raw2, 0, 512 * sizeof(float), stream);

  wcvt_k<<<784, 256, 0, stream>>>(q_w, kv_w, proj_w, mproj_w, fc1_w, fc2_w,
                                  qwb, kvwb, pwb, mwb, f1wb, f2wb);
  bn1_stats_k<<<256, 256, 0, stream>>>(x, g1, b1, st1);
  norm1_t_k<<<dim3(8, 32, 8), dim3(32, 8), 0, stream>>>(x, st1, xn32, xnb);

  // q = (xn @ q_w^T) * scale (bf16)
  mgemm_k<0, 64><<<dim3(4, 64), 256, 0, stream>>>(
      xnb, qwb, nullptr, qb, nullptr, nullptr, nullptr, nullptr, nullptr,
      256, 256);
  // kv = xr @ kv_w^T : K half -> kb row-major; V half -> vt transposed
  mgemm_k<1, 128><<<dim3(4, 64), 256, 0, stream>>>(
      xnb, kvwb, nullptr, kb, nullptr, nullptr, nullptr, nullptr, vt,
      256, 512);
  ce_k<<<4096, 256, 0, stream>>>(cor, cor_w, ceb);
  cet_k<<<dim3(64, 4), 256, 0, stream>>>(cor, cor_w, vt);

  attn_k<<<dim3(64, 8), 256, 0, stream>>>(qb, kb, vt, ceb, av, dmc);

  // xn2 = xn + av @ proj_w^T + proj_b (f32)
  mgemm_k<2, 64><<<dim3(4, 64), 256, 0, stream>>>(
      av, pwb, proj_b, xn2, xn32, nullptr, nullptr, nullptr, nullptr,
      256, 256);
  // motion = dmc @ mproj_w^T + mproj_b (f32, direct to out1)
  mgemm_k<3, 64><<<dim3(2, 64), 256, 0, stream>>>(
      dmc, mwb, mproj_b, out1, nullptr, nullptr, nullptr, nullptr, nullptr,
      128, 128);

  bn2_stats_k<<<64, 256, 0, stream>>>(xn2, raw2);
  bn2_final_k<<<1, 256, 0, stream>>>(raw2, g2, b2, st2);
  bn2_apply_k<<<2048, 256, 0, stream>>>(xn2, st2, xb);

  // h = prelu(dw(xb @ fc1_w^T + fc1_b)) (bf16)
  mgemm_k<4, 128><<<dim3(8, 64), 256, 0, stream>>>(
      xb, f1wb, fc1_b, hb, nullptr, dw_w, dw_b, prelu, nullptr, 256, HID_N);
  // x_out = x + (h @ fc2_w^T + fc2_b)^T (f32, transposed float4 store)
  mgemm_k<5, 64><<<dim3(4, 64), 256, 0, stream>>>(
      hb, f2wb, fc2_b, out0, x, nullptr, nullptr, nullptr, nullptr,
      HID_N, 256);
}

// Round 5
// 146.868 us; speedup vs baseline: 5.9164x; 1.0623x over previous
//
#include <hip/hip_runtime.h>
#include <hip/hip_bf16.h>
#include <math.h>

// MotionFormerBlock: bf16 MFMA GEMMs + bf16 MFMA flash attention (Vt-precomp).
// Shapes fixed: B=8, N=1024, C=DIM=256, MDIM=128, H=8, HD=32, MHD=16, HID=1024.
#define C_DIM 256
#define N_PTS 1024
#define H_N 8
#define MDIM_N 128
#define HID_N 1024
#define EPSV 1e-5f
#define R_TOT 8192
#define CN 262144               // C_DIM * N_PTS

typedef __bf16 bf16x8 __attribute__((ext_vector_type(8)));
typedef float f32x4 __attribute__((ext_vector_type(4)));

__device__ inline unsigned short bfu(float f) {
  union { __bf16 h; unsigned short u; } c;
  c.h = (__bf16)f;
  return c.u;
}

// ---------------------------------------------------------------- weight cvt
__global__ __launch_bounds__(256)
void wcvt_k(const float* __restrict__ s0, const float* __restrict__ s1,
            const float* __restrict__ s2, const float* __restrict__ s3,
            const float* __restrict__ s4, const float* __restrict__ s5,
            __bf16* d0, __bf16* d1, __bf16* d2, __bf16* d3, __bf16* d4,
            __bf16* d5) {
  int i = blockIdx.x * 256 + threadIdx.x;
  const float* s; __bf16* d; int off;
  if      (i <  16384) { s = s0; d = d0; off = 0; }
  else if (i <  49152) { s = s1; d = d1; off = 16384; }
  else if (i <  65536) { s = s2; d = d2; off = 49152; }
  else if (i <  69632) { s = s3; d = d3; off = 65536; }
  else if (i < 135168) { s = s4; d = d4; off = 69632; }
  else                 { s = s5; d = d5; off = 135168; }
  int j = i - off;
  float4 v = ((const float4*)s)[j];
  ushort4 u;
  u.x = bfu(v.x); u.y = bfu(v.y); u.z = bfu(v.z); u.w = bfu(v.w);
  ((ushort4*)d)[j] = u;
}

// ---------------------------------------------------------------- BN1 stats
__global__ __launch_bounds__(256)
void bn1_stats_k(const float* __restrict__ x, const float* __restrict__ g,
                 const float* __restrict__ bb, float* __restrict__ st) {
  int c = blockIdx.x;
  int t = threadIdx.x;
  float s = 0.f, q = 0.f;
  for (int i = 0; i < 32; ++i) {
    int idx = t + i * 256;
    int b = idx >> 10, n = idx & 1023;
    float v = x[(size_t)b * CN + (size_t)c * N_PTS + n];
    s += v; q += v * v;
  }
  __shared__ float ss[256], sq[256];
  ss[t] = s; sq[t] = q;
  __syncthreads();
  for (int off = 128; off > 0; off >>= 1) {
    if (t < off) { ss[t] += ss[t + off]; sq[t] += sq[t + off]; }
    __syncthreads();
  }
  if (t == 0) {
    float mean = ss[0] * (1.f / 8192.f);
    float var  = sq[0] * (1.f / 8192.f) - mean * mean;
    float sc   = g[c] * rsqrtf(var + EPSV);
    st[c]          = sc;
    st[C_DIM + c]  = bb[c] - mean * sc;
  }
}

// ------------------------------------------- normalize + transpose to tokens
__global__ __launch_bounds__(256)
void norm1_t_k(const float* __restrict__ x, const float* __restrict__ st,
               float* __restrict__ xn, __bf16* __restrict__ xnb) {
  __shared__ float tile[32][33];
  int c0 = blockIdx.x * 32, n0 = blockIdx.y * 32, b = blockIdx.z;
  int tx = threadIdx.x, ty = threadIdx.y;
#pragma unroll
  for (int k = 0; k < 4; ++k) {
    int ci = ty + k * 8;
    int c = c0 + ci;
    float v = x[(size_t)b * CN + (size_t)c * N_PTS + n0 + tx];
    tile[ci][tx] = v * st[c] + st[C_DIM + c];
  }
  __syncthreads();
#pragma unroll
  for (int k = 0; k < 4; ++k) {
    int ni = ty + k * 8;
    size_t o = ((size_t)(b * N_PTS + n0 + ni)) * C_DIM + c0 + tx;
    float v = tile[tx][ni];
    xn[o] = v;
    xnb[o] = (__bf16)v;
  }
}

// ---------------------------------------------------------------- ce = cor @ cor_w^T
__global__ __launch_bounds__(256)
void ce_k(const float* __restrict__ cor, const float* __restrict__ cw,
          float* __restrict__ ce) {
  int t = threadIdx.x;
  int r = blockIdx.x * 2 + (t >> 7);
  int j = t & 127;
  float c0 = cor[r * 3 + 0], c1 = cor[r * 3 + 1], c2 = cor[r * 3 + 2];
  ce[(size_t)r * MDIM_N + j] =
      c0 * cw[j * 3 + 0] + c1 * cw[j * 3 + 1] + c2 * cw[j * 3 + 2];
}

// --------------------------------------- ceh transposed into vt rows 32..47
__global__ __launch_bounds__(256)
void cet_k(const float* __restrict__ cor, const float* __restrict__ cw,
           __bf16* __restrict__ vt) {
  __shared__ float cs[768];           // 256 tokens x 3
  int bh = blockIdx.x; int b = bh >> 3, h = bh & 7;
  int n0 = blockIdx.y * 256;
  int t = threadIdx.x;
  for (int i = t; i < 768; i += 256)
    cs[i] = cor[(size_t)(b * N_PTS + n0) * 3 + i];
  __syncthreads();
  int md = t >> 4, ns = (t & 15) * 16;
  float w0 = cw[(h * 16 + md) * 3 + 0];
  float w1 = cw[(h * 16 + md) * 3 + 1];
  float w2 = cw[(h * 16 + md) * 3 + 2];
  __bf16* dst = &vt[((size_t)bh * 48 + 32 + md) * 1024 + n0 + ns];
#pragma unroll
  for (int g2 = 0; g2 < 4; ++g2) {
    ushort4 u;
    float v0 = cs[(ns + g2 * 4 + 0) * 3] * w0 + cs[(ns + g2 * 4 + 0) * 3 + 1] * w1 + cs[(ns + g2 * 4 + 0) * 3 + 2] * w2;
    float v1 = cs[(ns + g2 * 4 + 1) * 3] * w0 + cs[(ns + g2 * 4 + 1) * 3 + 1] * w1 + cs[(ns + g2 * 4 + 1) * 3 + 2] * w2;
    float v2 = cs[(ns + g2 * 4 + 2) * 3] * w0 + cs[(ns + g2 * 4 + 2) * 3 + 1] * w1 + cs[(ns + g2 * 4 + 2) * 3 + 2] * w2;
    float v3 = cs[(ns + g2 * 4 + 3) * 3] * w0 + cs[(ns + g2 * 4 + 3) * 3 + 1] * w1 + cs[(ns + g2 * 4 + 3) * 3 + 2] * w2;
    u.x = bfu(v0); u.y = bfu(v1); u.z = bfu(v2); u.w = bfu(v3);
    *(ushort4*)&dst[g2 * 4] = u;
  }
}

// ---------------------------------------------------------------- MFMA attention
// 8 waves x 16 q-rows per block (512 thr), one (b,h); K row-major from kb,
// V' pre-transposed from vt. bf16 Pbuf: write scalar bf16, reload as A-frag.
__global__ __launch_bounds__(512)
void attn_k(const __bf16* __restrict__ qb, const __bf16* __restrict__ kb,
            const __bf16* __restrict__ vt, const float* __restrict__ ceb,
            __bf16* __restrict__ av, __bf16* __restrict__ dmc) {
  __shared__ __bf16 KsV[64][40];      // 5.1 KB
  __shared__ __bf16 VtV[48][72];      // 6.9 KB
  __shared__ __bf16 Pbuf[8][16][72];  // 18.4 KB

  int bh = blockIdx.x; int b = bh >> 3, h = bh & 7;
  int t = threadIdx.x;
  int w = t >> 6, lane = t & 63;
  int l15 = lane & 15, g = lane >> 4;

  int qrow0 = b * N_PTS + blockIdx.y * 128 + w * 16;
  bf16x8 aq = *(const bf16x8*)&qb[(size_t)(qrow0 + l15) * C_DIM + h * 32 +
                                  g * 8];

  float mrun[4], lrun[4];
  f32x4 accf[3];
#pragma unroll
  for (int r = 0; r < 4; ++r) { mrun[r] = -1e30f; lrun[r] = 0.f; }
#pragma unroll
  for (int nt = 0; nt < 3; ++nt) accf[nt] = (f32x4){0.f, 0.f, 0.f, 0.f};

  for (int kt = 0; kt < 16; ++kt) {
    int key0 = kt * 64;
    __syncthreads();
    if (t >= 384) {
      // K tile: 64 keys x 32 d; 128 threads x 32B
      int tt = t - 384;
      int j = tt >> 1, c0 = (tt & 1) * 2;
      const uint4* src =
          (const uint4*)&kb[(size_t)(b * N_PTS + key0 + j) * 256 + h * 32];
      *(uint4*)&KsV[j][c0 * 8]       = src[c0];
      *(uint4*)&KsV[j][(c0 + 1) * 8] = src[c0 + 1];
    } else {
      // V' tile: 48 dv x 64 keys; 384 threads x 16B
      int dv = t >> 3, kg = t & 7;
      *(uint4*)&VtV[dv][kg * 8] =
          *(const uint4*)&vt[((size_t)bh * 48 + dv) * 1024 + key0 + kg * 8];
    }
    __syncthreads();

    // S = Q K^T (scale pre-folded into qb)
    float sv[4][4];
#pragma unroll
    for (int nt = 0; nt < 4; ++nt) {
      bf16x8 bk = *(const bf16x8*)&KsV[nt * 16 + l15][g * 8];
      f32x4 z = (f32x4){0.f, 0.f, 0.f, 0.f};
      f32x4 s0 = __builtin_amdgcn_mfma_f32_16x16x32_bf16(aq, bk, z, 0, 0, 0);
#pragma unroll
      for (int r = 0; r < 4; ++r) sv[nt][r] = s0[r];
    }

    // online softmax + bf16 P write
#pragma unroll
    for (int r = 0; r < 4; ++r) {
      float tm = fmaxf(fmaxf(sv[0][r], sv[1][r]), fmaxf(sv[2][r], sv[3][r]));
#pragma unroll
      for (int o = 1; o <= 8; o <<= 1) tm = fmaxf(tm, __shfl_xor(tm, o));
      float nm = fmaxf(mrun[r], tm);
      float corr = __expf(mrun[r] - nm);
      mrun[r] = nm;
      float rs = 0.f;
#pragma unroll
      for (int nt = 0; nt < 4; ++nt) {
        float p = __expf(sv[nt][r] - nm);
        sv[nt][r] = p;
        rs += p;
      }
#pragma unroll
      for (int o = 1; o <= 8; o <<= 1) rs += __shfl_xor(rs, o);
      lrun[r] = lrun[r] * corr + rs;
#pragma unroll
      for (int nt = 0; nt < 3; ++nt) accf[nt][r] *= corr;
      int prow = g * 4 + r;
#pragma unroll
      for (int nt = 0; nt < 4; ++nt)
        Pbuf[w][prow][nt * 16 + l15] = (__bf16)sv[nt][r];
    }

    // reload P as A fragments (wave-internal; bf16 direct)
    bf16x8 ap[2];
#pragma unroll
    for (int kc = 0; kc < 2; ++kc)
      ap[kc] = *(const bf16x8*)&Pbuf[w][l15][kc * 32 + g * 8];

    // PV
#pragma unroll
    for (int nt = 0; nt < 3; ++nt)
#pragma unroll
      for (int kc = 0; kc < 2; ++kc) {
        bf16x8 bv = *(const bf16x8*)&VtV[nt * 16 + l15][kc * 32 + g * 8];
        accf[nt] = __builtin_amdgcn_mfma_f32_16x16x32_bf16(ap[kc], bv,
                                                           accf[nt], 0, 0, 0);
      }
  }

  // epilogue
#pragma unroll
  for (int r = 0; r < 4; ++r) {
    float inv = 1.f / lrun[r];
    int row = qrow0 + g * 4 + r;
    av[(size_t)row * C_DIM + h * 32 + l15]      = (__bf16)(accf[0][r] * inv);
    av[(size_t)row * C_DIM + h * 32 + 16 + l15] = (__bf16)(accf[1][r] * inv);
    size_t ci = (size_t)row * MDIM_N + h * 16 + l15;
    dmc[ci] = (__bf16)(accf[2][r] * inv - ceb[ci]);
  }
}

// ---------------------------------------------------------------- MFMA GEMM
// MODE 0: out bf16 * softmax-scale (q)
// MODE 1: A batch-swapped; m<256 -> kb row-major bf16; m>=256 -> vt transposed
// MODE 2: out f32 = e0+acc+bias (proj->xn2)
// MODE 3: out f32 = acc+bias (motion)
// MODE 4: dw+PReLU epilogue, out bf16 (fc1)
// MODE 5: transposed float4 residual store (fc2)
template <int MODE, int BNt>
__global__ __launch_bounds__(256)
void mgemm_k(const __bf16* __restrict__ A, const __bf16* __restrict__ W,
             const float* __restrict__ bias, void* __restrict__ outp,
             const float* __restrict__ e0, const float* __restrict__ e2,
             const float* __restrict__ e3, const float* __restrict__ pre,
             __bf16* __restrict__ vtp, int K, int M) {
  constexpr int WN = BNt / 2;
  constexpr int NR = WN / 16;
  __shared__ __bf16 Al[128 * 64];
  __shared__ __bf16 Bl[BNt * 64];
  int t = threadIdx.x;
  int w = t >> 6, lane = t & 63;
  int l15 = lane & 15, g = lane >> 4;
  int wr = w >> 1, wn = w & 1;
  int r0 = blockIdx.y * 128;
  int m0 = blockIdx.x * BNt;

  f32x4 acc[4][NR];
#pragma unroll
  for (int i = 0; i < 4; ++i)
#pragma unroll
    for (int j = 0; j < NR; ++j) acc[i][j] = (f32x4){0.f, 0.f, 0.f, 0.f};

  for (int kt = 0; kt < K; kt += 64) {
    __syncthreads();
#pragma unroll
    for (int p = 0; p < 4; ++p) {
      int flat = p * 256 + t;
      int row = flat >> 3, c16 = flat & 7;
      int gr = r0 + row;
      if (MODE == 1) {
        int b = gr >> 10;
        gr = (((b + 4) & 7) << 10) | (gr & 1023);
      }
      *(uint4*)&Al[row * 64 + (c16 ^ (row & 7)) * 8] =
          *(const uint4*)&A[(size_t)gr * K + kt + c16 * 8];
    }
#pragma unroll
    for (int p = 0; p < BNt / 32; ++p) {
      int flat = p * 256 + t;
      int row = flat >> 3, c16 = flat & 7;
      *(uint4*)&Bl[row * 64 + (c16 ^ (row & 7)) * 8] =
          *(const uint4*)&W[(size_t)(m0 + row) * K + kt + c16 * 8];
    }
    __syncthreads();
#pragma unroll
    for (int ks = 0; ks < 2; ++ks) {
      bf16x8 af[4], bf_[NR];
#pragma unroll
      for (int mf = 0; mf < 4; ++mf) {
        int row = wr * 64 + mf * 16 + l15;
        af[mf] = *(const bf16x8*)&Al[row * 64 + ((ks * 4 + g) ^ (l15 & 7)) * 8];
      }
#pragma unroll
      for (int nf = 0; nf < NR; ++nf) {
        int row = wn * WN + nf * 16 + l15;
        bf_[nf] = *(const bf16x8*)&Bl[row * 64 + ((ks * 4 + g) ^ (l15 & 7)) * 8];
      }
#pragma unroll
      for (int mf = 0; mf < 4; ++mf)
#pragma unroll
        for (int nf = 0; nf < NR; ++nf)
          acc[mf][nf] = __builtin_amdgcn_mfma_f32_16x16x32_bf16(
              af[mf], bf_[nf], acc[mf][nf], 0, 0, 0);
    }
  }

  float a_pre = (MODE == 4) ? pre[0] : 0.f;
#pragma unroll
  for (int mf = 0; mf < 4; ++mf) {
#pragma unroll
    for (int nf = 0; nf < NR; ++nf) {
      int m = m0 + wn * WN + nf * 16 + l15;
      int rbase = r0 + wr * 64 + mf * 16 + g * 4;
      if (MODE == 5) {
        int b = rbase >> 10, n = rbase & 1023;
        size_t oi = (size_t)b * CN + (size_t)m * N_PTS + n;
        float4 xv = *(const float4*)&e0[oi];
        float bs = bias[m];
        float4 ov;
        ov.x = xv.x + acc[mf][nf][0] + bs;
        ov.y = xv.y + acc[mf][nf][1] + bs;
        ov.z = xv.z + acc[mf][nf][2] + bs;
        ov.w = xv.w + acc[mf][nf][3] + bs;
        *(float4*)&((float*)outp)[oi] = ov;
      } else if (MODE == 1 && m >= 256) {
        int d = m - 256, hh = d >> 5, dd = d & 31;
        int b = rbase >> 10, n0v = rbase & 1023;
        ushort4 u;
        u.x = bfu(acc[mf][nf][0]); u.y = bfu(acc[mf][nf][1]);
        u.z = bfu(acc[mf][nf][2]); u.w = bfu(acc[mf][nf][3]);
        *(ushort4*)&vtp[(((size_t)b * 8 + hh) * 48 + dd) * 1024 + n0v] = u;
      } else {
#pragma unroll
        for (int r = 0; r < 4; ++r) {
          float v = acc[mf][nf][r];
          if (MODE == 0) {
            ((__bf16*)outp)[(size_t)(rbase + r) * M + m] =
                (__bf16)(v * 0.17677669529663687f);
          } else if (MODE == 1) {
            ((__bf16*)outp)[(size_t)(rbase + r) * 256 + m] = (__bf16)v;
          } else if (MODE == 2) {
            size_t oi = (size_t)(rbase + r) * M + m;
            ((float*)outp)[oi] = e0[oi] + v + bias[m];
          } else if (MODE == 3) {
            ((float*)outp)[(size_t)(rbase + r) * M + m] = v + bias[m];
          } else if (MODE == 4) {
            v += bias[m];
            v = v * e2[m] + e3[m];
            ((__bf16*)outp)[(size_t)(rbase + r) * M + m] =
                (__bf16)(v >= 0.f ? v : a_pre * v);
          }
        }
      }
    }
  }
}

// ---------------------------------------------------------------- BN2
__global__ __launch_bounds__(256)
void bn2_stats_k(const float* __restrict__ xn2, float* __restrict__ raw) {
  int t = threadIdx.x;
  float s = 0.f, q = 0.f;
  int r0 = blockIdx.x * 128;
  for (int i = 0; i < 128; ++i) {
    float v = xn2[(size_t)(r0 + i) * C_DIM + t];
    s += v; q += v * v;
  }
  atomicAdd(&raw[t], s);
  atomicAdd(&raw[C_DIM + t], q);
}

__global__ __launch_bounds__(256)
void bn2_final_k(const float* __restrict__ raw, const float* __restrict__ g,
                 const float* __restrict__ bb, float* __restrict__ st) {
  int c = threadIdx.x;
  float mean = raw[c] * (1.f / 8192.f);
  float var  = raw[C_DIM + c] * (1.f / 8192.f) - mean * mean;
  float sc   = g[c] * rsqrtf(var + EPSV);
  st[c]         = sc;
  st[C_DIM + c] = bb[c] - mean * sc;
}

__global__ __launch_bounds__(256)
void bn2_apply_k(const float* __restrict__ xn2, const float* __restrict__ st,
                 __bf16* __restrict__ xb) {
  int i = blockIdx.x * 256 + threadIdx.x;
  float4 v = ((const float4*)xn2)[i];
  int c = (i * 4) & 255;
  ushort4 u;
  u.x = bfu(v.x * st[c]     + st[C_DIM + c]);
  u.y = bfu(v.y * st[c + 1] + st[C_DIM + c + 1]);
  u.z = bfu(v.z * st[c + 2] + st[C_DIM + c + 2]);
  u.w = bfu(v.w * st[c + 3] + st[C_DIM + c + 3]);
  ((ushort4*)xb)[i] = u;
}

extern "C" void kernel_launch(void* const* d_in, const int* in_sizes, int n_in,
                              void* d_out, int out_size, void* d_ws,
                              size_t ws_size, hipStream_t stream) {
  const float* x       = (const float*)d_in[0];
  const float* cor     = (const float*)d_in[1];
  const float* q_w     = (const float*)d_in[2];
  const float* kv_w    = (const float*)d_in[3];
  const float* cor_w   = (const float*)d_in[4];
  const float* proj_w  = (const float*)d_in[5];
  const float* proj_b  = (const float*)d_in[6];
  const float* mproj_w = (const float*)d_in[7];
  const float* mproj_b = (const float*)d_in[8];
  const float* g1      = (const float*)d_in[9];
  const float* b1      = (const float*)d_in[10];
  const float* g2      = (const float*)d_in[11];
  const float* b2      = (const float*)d_in[12];
  const float* fc1_w   = (const float*)d_in[13];
  const float* fc1_b   = (const float*)d_in[14];
  const float* dw_w    = (const float*)d_in[15];
  const float* dw_b    = (const float*)d_in[16];
  const float* prelu   = (const float*)d_in[17];
  const float* fc2_w   = (const float*)d_in[18];
  const float* fc2_b   = (const float*)d_in[19];

  char* base = (char*)d_ws;
  const size_t MB = 1u << 20;
  float*  xn32 = (float*)(base + 0);             // 0-8 MB  f32
  __bf16* xnb  = (__bf16*)(base + 8 * MB);       // 8-12
  __bf16* qb   = (__bf16*)(base + 12 * MB);      // 12-16
  __bf16* kb   = (__bf16*)(base + 16 * MB);      // 16-20
  __bf16* vt   = (__bf16*)(base + 20 * MB);      // 20-26 (64*48*1024 bf16)
  float*  ceb  = (float*)(base + 26 * MB);       // 26-30 f32
  __bf16* av   = (__bf16*)(base + 30 * MB);      // 30-34
  __bf16* dmc  = (__bf16*)(base + 34 * MB);      // 34-36
  float*  xn2  = (float*)(base + 36 * MB);       // 36-44 f32
  __bf16* xb   = (__bf16*)(base + 8 * MB);       // overlay xnb (dead post-kv)
  __bf16* hb   = (__bf16*)(base + 12 * MB);      // overlay 12-28 (fc1 out)
  __bf16* qwb  = (__bf16*)(base + 44 * MB);
  __bf16* kvwb = (__bf16*)(base + 44 * MB + 131072);
  __bf16* pwb  = (__bf16*)(base + 44 * MB + 393216);
  __bf16* mwb  = (__bf16*)(base + 44 * MB + 524288);
  __bf16* f1wb = (__bf16*)(base + 44 * MB + 557056);
  __bf16* f2wb = (__bf16*)(base + 44 * MB + 1081344);
  float*  st1  = (float*)(base + 45 * MB + 655360);
  float*  raw2 = st1 + 1024;
  float*  st2  = st1 + 2048;
  float* out0 = (float*)d_out;
  float* out1 = out0 + 2097152;

  hipMemsetAsync(raw2, 0, 512 * sizeof(float), stream);

  wcvt_k<<<784, 256, 0, stream>>>(q_w, kv_w, proj_w, mproj_w, fc1_w, fc2_w,
                                  qwb, kvwb, pwb, mwb, f1wb, f2wb);
  bn1_stats_k<<<256, 256, 0, stream>>>(x, g1, b1, st1);
  norm1_t_k<<<dim3(8, 32, 8), dim3(32, 8), 0, stream>>>(x, st1, xn32, xnb);

  // q = (xn @ q_w^T) * scale (bf16)
  mgemm_k<0, 64><<<dim3(4, 64), 256, 0, stream>>>(
      xnb, qwb, nullptr, qb, nullptr, nullptr, nullptr, nullptr, nullptr,
      256, 256);
  // kv = xr @ kv_w^T : K half -> kb row-major; V half -> vt transposed
  mgemm_k<1, 128><<<dim3(4, 64), 256, 0, stream>>>(
      xnb, kvwb, nullptr, kb, nullptr, nullptr, nullptr, nullptr, vt,
      256, 512);
  ce_k<<<4096, 256, 0, stream>>>(cor, cor_w, ceb);
  cet_k<<<dim3(64, 4), 256, 0, stream>>>(cor, cor_w, vt);

  attn_k<<<dim3(64, 8), 512, 0, stream>>>(qb, kb, vt, ceb, av, dmc);

  // xn2 = xn + av @ proj_w^T + proj_b (f32)
  mgemm_k<2, 64><<<dim3(4, 64), 256, 0, stream>>>(
      av, pwb, proj_b, xn2, xn32, nullptr, nullptr, nullptr, nullptr,
      256, 256);
  // motion = dmc @ mproj_w^T + mproj_b (f32, direct to out1)
  mgemm_k<3, 64><<<dim3(2, 64), 256, 0, stream>>>(
      dmc, mwb, mproj_b, out1, nullptr, nullptr, nullptr, nullptr, nullptr,
      128, 128);

  bn2_stats_k<<<64, 256, 0, stream>>>(xn2, raw2);
  bn2_final_k<<<1, 256, 0, stream>>>(raw2, g2, b2, st2);
  bn2_apply_k<<<2048, 256, 0, stream>>>(xn2, st2, xb);

  // h = prelu(dw(xb @ fc1_w^T + fc1_b)) (bf16)
  mgemm_k<4, 128><<<dim3(8, 64), 256, 0, stream>>>(
      xb, f1wb, fc1_b, hb, nullptr, dw_w, dw_b, prelu, nullptr, 256, HID_N);
  // x_out = x + (h @ fc2_w^T + fc2_b)^T (f32, transposed float4 store)
  mgemm_k<5, 64><<<dim3(4, 64), 256, 0, stream>>>(
      hb, f2wb, fc2_b, out0, x, nullptr, nullptr, nullptr, nullptr,
      HID_N, 256);
}

// Round 6
// 143.221 us; speedup vs baseline: 6.0670x; 1.0255x over previous
//
#include <hip/hip_runtime.h>
#include <hip/hip_bf16.h>
#include <math.h>

// MotionFormerBlock: bf16 MFMA GEMMs + dbuf bf16 MFMA flash attention.
// Shapes fixed: B=8, N=1024, C=DIM=256, MDIM=128, H=8, HD=32, MHD=16, HID=1024.
#define C_DIM 256
#define N_PTS 1024
#define H_N 8
#define MDIM_N 128
#define HID_N 1024
#define EPSV 1e-5f
#define R_TOT 8192
#define CN 262144               // C_DIM * N_PTS

typedef __bf16 bf16x8 __attribute__((ext_vector_type(8)));
typedef float f32x4 __attribute__((ext_vector_type(4)));

__device__ inline unsigned short bfu(float f) {
  union { __bf16 h; unsigned short u; } c;
  c.h = (__bf16)f;
  return c.u;
}

// ---------------------------------------------------------------- weight cvt
__global__ __launch_bounds__(256)
void wcvt_k(const float* __restrict__ s0, const float* __restrict__ s1,
            const float* __restrict__ s2, const float* __restrict__ s3,
            const float* __restrict__ s4, const float* __restrict__ s5,
            __bf16* d0, __bf16* d1, __bf16* d2, __bf16* d3, __bf16* d4,
            __bf16* d5) {
  int i = blockIdx.x * 256 + threadIdx.x;
  const float* s; __bf16* d; int off;
  if      (i <  16384) { s = s0; d = d0; off = 0; }
  else if (i <  49152) { s = s1; d = d1; off = 16384; }
  else if (i <  65536) { s = s2; d = d2; off = 49152; }
  else if (i <  69632) { s = s3; d = d3; off = 65536; }
  else if (i < 135168) { s = s4; d = d4; off = 69632; }
  else                 { s = s5; d = d5; off = 135168; }
  int j = i - off;
  float4 v = ((const float4*)s)[j];
  ushort4 u;
  u.x = bfu(v.x); u.y = bfu(v.y); u.z = bfu(v.z); u.w = bfu(v.w);
  ((ushort4*)d)[j] = u;
}

// ---------------------------------------------------------------- BN1 stats
__global__ __launch_bounds__(256)
void bn1_stats_k(const float* __restrict__ x, const float* __restrict__ g,
                 const float* __restrict__ bb, float* __restrict__ st) {
  int c = blockIdx.x;
  int t = threadIdx.x;
  float s = 0.f, q = 0.f;
  for (int i = 0; i < 32; ++i) {
    int idx = t + i * 256;
    int b = idx >> 10, n = idx & 1023;
    float v = x[(size_t)b * CN + (size_t)c * N_PTS + n];
    s += v; q += v * v;
  }
  __shared__ float ss[256], sq[256];
  ss[t] = s; sq[t] = q;
  __syncthreads();
  for (int off = 128; off > 0; off >>= 1) {
    if (t < off) { ss[t] += ss[t + off]; sq[t] += sq[t + off]; }
    __syncthreads();
  }
  if (t == 0) {
    float mean = ss[0] * (1.f / 8192.f);
    float var  = sq[0] * (1.f / 8192.f) - mean * mean;
    float sc   = g[c] * rsqrtf(var + EPSV);
    st[c]          = sc;
    st[C_DIM + c]  = bb[c] - mean * sc;
  }
}

// ------------------------------------------- normalize + transpose to tokens
__global__ __launch_bounds__(256)
void norm1_t_k(const float* __restrict__ x, const float* __restrict__ st,
               float* __restrict__ xn, __bf16* __restrict__ xnb) {
  __shared__ float tile[32][33];
  int c0 = blockIdx.x * 32, n0 = blockIdx.y * 32, b = blockIdx.z;
  int tx = threadIdx.x, ty = threadIdx.y;
#pragma unroll
  for (int k = 0; k < 4; ++k) {
    int ci = ty + k * 8;
    int c = c0 + ci;
    float v = x[(size_t)b * CN + (size_t)c * N_PTS + n0 + tx];
    tile[ci][tx] = v * st[c] + st[C_DIM + c];
  }
  __syncthreads();
#pragma unroll
  for (int k = 0; k < 4; ++k) {
    int ni = ty + k * 8;
    size_t o = ((size_t)(b * N_PTS + n0 + ni)) * C_DIM + c0 + tx;
    float v = tile[tx][ni];
    xn[o] = v;
    xnb[o] = (__bf16)v;
  }
}

// --------------------------------------- ceh transposed into vt rows 32..47
__global__ __launch_bounds__(256)
void cet_k(const float* __restrict__ cor, const float* __restrict__ cw,
           __bf16* __restrict__ vt) {
  __shared__ float cs[768];           // 256 tokens x 3
  int bh = blockIdx.x; int b = bh >> 3, h = bh & 7;
  int n0 = blockIdx.y * 256;
  int t = threadIdx.x;
  for (int i = t; i < 768; i += 256)
    cs[i] = cor[(size_t)(b * N_PTS + n0) * 3 + i];
  __syncthreads();
  int md = t >> 4, ns = (t & 15) * 16;
  float w0 = cw[(h * 16 + md) * 3 + 0];
  float w1 = cw[(h * 16 + md) * 3 + 1];
  float w2 = cw[(h * 16 + md) * 3 + 2];
  __bf16* dst = &vt[((size_t)bh * 48 + 32 + md) * 1024 + n0 + ns];
#pragma unroll
  for (int g2 = 0; g2 < 4; ++g2) {
    ushort4 u;
    float v0 = cs[(ns + g2 * 4 + 0) * 3] * w0 + cs[(ns + g2 * 4 + 0) * 3 + 1] * w1 + cs[(ns + g2 * 4 + 0) * 3 + 2] * w2;
    float v1 = cs[(ns + g2 * 4 + 1) * 3] * w0 + cs[(ns + g2 * 4 + 1) * 3 + 1] * w1 + cs[(ns + g2 * 4 + 1) * 3 + 2] * w2;
    float v2 = cs[(ns + g2 * 4 + 2) * 3] * w0 + cs[(ns + g2 * 4 + 2) * 3 + 1] * w1 + cs[(ns + g2 * 4 + 2) * 3 + 2] * w2;
    float v3 = cs[(ns + g2 * 4 + 3) * 3] * w0 + cs[(ns + g2 * 4 + 3) * 3 + 1] * w1 + cs[(ns + g2 * 4 + 3) * 3 + 2] * w2;
    u.x = bfu(v0); u.y = bfu(v1); u.z = bfu(v2); u.w = bfu(v3);
    *(ushort4*)&dst[g2 * 4] = u;
  }
}

// ---------------------------------------------------------------- MFMA attention
// 8 waves x 16 q-rows (512 thr), one (b,h) per blockIdx.x. Q/K head-major
// [bh][n][32]; V' pre-transposed [bh][48][1024]. Double-buffered K/V staging,
// ONE barrier per tile; next-tile global loads issued before compute.
__global__ __launch_bounds__(512)
void attn_k(const __bf16* __restrict__ qb, const __bf16* __restrict__ kb,
            const __bf16* __restrict__ vt, const float* __restrict__ cor,
            const float* __restrict__ cw, __bf16* __restrict__ av,
            __bf16* __restrict__ dmc) {
  __shared__ __bf16 KsV[2][64][40];   // 10.2 KB
  __shared__ __bf16 VtV[2][48][72];   // 13.8 KB
  __shared__ __bf16 Pbuf[8][16][72];  // 18.4 KB

  int bh = blockIdx.x; int b = bh >> 3, h = bh & 7;
  int t = threadIdx.x;
  int w = t >> 6, lane = t & 63;
  int l15 = lane & 15, g = lane >> 4;

  int nloc0 = blockIdx.y * 128 + w * 16;
  bf16x8 aq =
      *(const bf16x8*)&qb[((size_t)bh * N_PTS + nloc0 + l15) * 32 + g * 8];

  const __bf16* ksrc = kb + (size_t)bh * N_PTS * 32;   // [1024][32]
  const __bf16* vsrc = vt + (size_t)bh * 48 * N_PTS;   // [48][1024]
  int u = t - 256;                // V-stage thread id (0..255)
  int vdv = u >> 3, vkg = u & 7;  // task1: rows 0..31
  // task2 (u<128): rows 32..47

  float mrun[4], lrun[4];
  f32x4 accf[3];
#pragma unroll
  for (int r = 0; r < 4; ++r) { mrun[r] = -1e30f; lrun[r] = 0.f; }
#pragma unroll
  for (int nt = 0; nt < 3; ++nt) accf[nt] = (f32x4){0.f, 0.f, 0.f, 0.f};

  // prologue: stage tile 0 into buffer 0
  if (t < 256) {
    *(uint4*)&KsV[0][t >> 2][(t & 3) * 8] = *(const uint4*)&ksrc[t * 8];
  } else {
    *(uint4*)&VtV[0][vdv][vkg * 8] =
        *(const uint4*)&vsrc[(size_t)vdv * N_PTS + vkg * 8];
    if (u < 128)
      *(uint4*)&VtV[0][32 + vdv][vkg * 8] =
          *(const uint4*)&vsrc[(size_t)(32 + vdv) * N_PTS + vkg * 8];
  }
  __syncthreads();

  for (int kt = 0; kt < 16; ++kt) {
    int cur = kt & 1, nxt = cur ^ 1;
    // issue next-tile loads (results consumed after compute)
    uint4 kreg, vreg0, vreg1;
    if (kt < 15) {
      int key1 = (kt + 1) * 64;
      if (t < 256) {
        kreg = *(const uint4*)&ksrc[key1 * 32 + t * 8];
      } else {
        vreg0 = *(const uint4*)&vsrc[(size_t)vdv * N_PTS + key1 + vkg * 8];
        if (u < 128)
          vreg1 =
              *(const uint4*)&vsrc[(size_t)(32 + vdv) * N_PTS + key1 + vkg * 8];
      }
    }

    // ---- S = Q K^T (scale pre-folded into qb)
    float sv[4][4];
    __builtin_amdgcn_s_setprio(1);
#pragma unroll
    for (int nt = 0; nt < 4; ++nt) {
      bf16x8 bk = *(const bf16x8*)&KsV[cur][nt * 16 + l15][g * 8];
      f32x4 z = (f32x4){0.f, 0.f, 0.f, 0.f};
      f32x4 s0 = __builtin_amdgcn_mfma_f32_16x16x32_bf16(aq, bk, z, 0, 0, 0);
#pragma unroll
      for (int r = 0; r < 4; ++r) sv[nt][r] = s0[r];
    }
    __builtin_amdgcn_s_setprio(0);

    // ---- online softmax + bf16 P write
#pragma unroll
    for (int r = 0; r < 4; ++r) {
      float tm = fmaxf(fmaxf(sv[0][r], sv[1][r]), fmaxf(sv[2][r], sv[3][r]));
#pragma unroll
      for (int o = 1; o <= 8; o <<= 1) tm = fmaxf(tm, __shfl_xor(tm, o));
      float nm = fmaxf(mrun[r], tm);
      float corr = __expf(mrun[r] - nm);
      mrun[r] = nm;
      float rs = 0.f;
#pragma unroll
      for (int nt = 0; nt < 4; ++nt) {
        float p = __expf(sv[nt][r] - nm);
        sv[nt][r] = p;
        rs += p;
      }
#pragma unroll
      for (int o = 1; o <= 8; o <<= 1) rs += __shfl_xor(rs, o);
      lrun[r] = lrun[r] * corr + rs;
#pragma unroll
      for (int nt = 0; nt < 3; ++nt) accf[nt][r] *= corr;
      int prow = g * 4 + r;
#pragma unroll
      for (int nt = 0; nt < 4; ++nt)
        Pbuf[w][prow][nt * 16 + l15] = (__bf16)sv[nt][r];
    }

    // ---- reload P as A fragments (wave-internal)
    bf16x8 ap[2];
#pragma unroll
    for (int kc = 0; kc < 2; ++kc)
      ap[kc] = *(const bf16x8*)&Pbuf[w][l15][kc * 32 + g * 8];

    // ---- PV
    __builtin_amdgcn_s_setprio(1);
#pragma unroll
    for (int nt = 0; nt < 3; ++nt)
#pragma unroll
      for (int kc = 0; kc < 2; ++kc) {
        bf16x8 bv = *(const bf16x8*)&VtV[cur][nt * 16 + l15][kc * 32 + g * 8];
        accf[nt] = __builtin_amdgcn_mfma_f32_16x16x32_bf16(ap[kc], bv,
                                                           accf[nt], 0, 0, 0);
      }
    __builtin_amdgcn_s_setprio(0);

    // ---- write staged regs into the other buffer; one barrier per tile
    if (kt < 15) {
      if (t < 256) {
        *(uint4*)&KsV[nxt][t >> 2][(t & 3) * 8] = kreg;
      } else {
        *(uint4*)&VtV[nxt][vdv][vkg * 8] = vreg0;
        if (u < 128) *(uint4*)&VtV[nxt][32 + vdv][vkg * 8] = vreg1;
      }
      __syncthreads();
    }
  }

  // ---- epilogue: normalize; av bf16 token-major; dmc = cr - ce (ce inline)
  float w0 = cw[(h * 16 + l15) * 3 + 0];
  float w1 = cw[(h * 16 + l15) * 3 + 1];
  float w2 = cw[(h * 16 + l15) * 3 + 2];
#pragma unroll
  for (int r = 0; r < 4; ++r) {
    float inv = 1.f / lrun[r];
    int nloc = nloc0 + g * 4 + r;
    int row = b * N_PTS + nloc;
    av[(size_t)row * C_DIM + h * 32 + l15]      = (__bf16)(accf[0][r] * inv);
    av[(size_t)row * C_DIM + h * 32 + 16 + l15] = (__bf16)(accf[1][r] * inv);
    const float* cp = &cor[(size_t)row * 3];
    float ce = cp[0] * w0 + cp[1] * w1 + cp[2] * w2;
    dmc[(size_t)row * MDIM_N + h * 16 + l15] =
        (__bf16)(accf[2][r] * inv - ce);
  }
}

// ---------------------------------------------------------------- MFMA GEMM
// MODE 0: out bf16 * softmax-scale, head-major [bh][n][32] (q)
// MODE 1: A batch-swapped; m<256 -> kb head-major; m>=256 -> vt transposed
// MODE 2: out f32 = e0+acc+bias (proj->xn2)
// MODE 3: out f32 = acc+bias (motion)
// MODE 4: dw+PReLU epilogue, out bf16 (fc1)
// MODE 5: transposed float4 residual store (fc2)
template <int MODE, int BNt>
__global__ __launch_bounds__(256)
void mgemm_k(const __bf16* __restrict__ A, const __bf16* __restrict__ W,
             const float* __restrict__ bias, void* __restrict__ outp,
             const float* __restrict__ e0, const float* __restrict__ e2,
             const float* __restrict__ e3, const float* __restrict__ pre,
             __bf16* __restrict__ vtp, int K, int M) {
  constexpr int WN = BNt / 2;
  constexpr int NR = WN / 16;
  __shared__ __bf16 Al[128 * 64];
  __shared__ __bf16 Bl[BNt * 64];
  int t = threadIdx.x;
  int w = t >> 6, lane = t & 63;
  int l15 = lane & 15, g = lane >> 4;
  int wr = w >> 1, wn = w & 1;
  int r0 = blockIdx.y * 128;
  int m0 = blockIdx.x * BNt;

  f32x4 acc[4][NR];
#pragma unroll
  for (int i = 0; i < 4; ++i)
#pragma unroll
    for (int j = 0; j < NR; ++j) acc[i][j] = (f32x4){0.f, 0.f, 0.f, 0.f};

  for (int kt = 0; kt < K; kt += 64) {
    __syncthreads();
#pragma unroll
    for (int p = 0; p < 4; ++p) {
      int flat = p * 256 + t;
      int row = flat >> 3, c16 = flat & 7;
      int gr = r0 + row;
      if (MODE == 1) {
        int b = gr >> 10;
        gr = (((b + 4) & 7) << 10) | (gr & 1023);
      }
      *(uint4*)&Al[row * 64 + (c16 ^ (row & 7)) * 8] =
          *(const uint4*)&A[(size_t)gr * K + kt + c16 * 8];
    }
#pragma unroll
    for (int p = 0; p < BNt / 32; ++p) {
      int flat = p * 256 + t;
      int row = flat >> 3, c16 = flat & 7;
      *(uint4*)&Bl[row * 64 + (c16 ^ (row & 7)) * 8] =
          *(const uint4*)&W[(size_t)(m0 + row) * K + kt + c16 * 8];
    }
    __syncthreads();
#pragma unroll
    for (int ks = 0; ks < 2; ++ks) {
      bf16x8 af[4], bf_[NR];
#pragma unroll
      for (int mf = 0; mf < 4; ++mf) {
        int row = wr * 64 + mf * 16 + l15;
        af[mf] = *(const bf16x8*)&Al[row * 64 + ((ks * 4 + g) ^ (l15 & 7)) * 8];
      }
#pragma unroll
      for (int nf = 0; nf < NR; ++nf) {
        int row = wn * WN + nf * 16 + l15;
        bf_[nf] = *(const bf16x8*)&Bl[row * 64 + ((ks * 4 + g) ^ (l15 & 7)) * 8];
      }
#pragma unroll
      for (int mf = 0; mf < 4; ++mf)
#pragma unroll
        for (int nf = 0; nf < NR; ++nf)
          acc[mf][nf] = __builtin_amdgcn_mfma_f32_16x16x32_bf16(
              af[mf], bf_[nf], acc[mf][nf], 0, 0, 0);
    }
  }

  float a_pre = (MODE == 4) ? pre[0] : 0.f;
#pragma unroll
  for (int mf = 0; mf < 4; ++mf) {
#pragma unroll
    for (int nf = 0; nf < NR; ++nf) {
      int m = m0 + wn * WN + nf * 16 + l15;
      int rbase = r0 + wr * 64 + mf * 16 + g * 4;
      if (MODE == 5) {
        int b = rbase >> 10, n = rbase & 1023;
        size_t oi = (size_t)b * CN + (size_t)m * N_PTS + n;
        float4 xv = *(const float4*)&e0[oi];
        float bs = bias[m];
        float4 ov;
        ov.x = xv.x + acc[mf][nf][0] + bs;
        ov.y = xv.y + acc[mf][nf][1] + bs;
        ov.z = xv.z + acc[mf][nf][2] + bs;
        ov.w = xv.w + acc[mf][nf][3] + bs;
        *(float4*)&((float*)outp)[oi] = ov;
      } else if (MODE == 1 && m >= 256) {
        int d = m - 256, hh = d >> 5, dd = d & 31;
        int b = rbase >> 10, n0v = rbase & 1023;
        ushort4 uu;
        uu.x = bfu(acc[mf][nf][0]); uu.y = bfu(acc[mf][nf][1]);
        uu.z = bfu(acc[mf][nf][2]); uu.w = bfu(acc[mf][nf][3]);
        *(ushort4*)&vtp[(((size_t)b * 8 + hh) * 48 + dd) * 1024 + n0v] = uu;
      } else {
#pragma unroll
        for (int r = 0; r < 4; ++r) {
          float v = acc[mf][nf][r];
          if (MODE == 0) {
            // head-major [bh][n][32], scale folded
            int b = rbase >> 10, n = (rbase & 1023) + r;
            int hh = m >> 5, dd = m & 31;
            ((__bf16*)outp)[(((size_t)b * 8 + hh) * 1024 + n) * 32 + dd] =
                (__bf16)(v * 0.17677669529663687f);
          } else if (MODE == 1) {
            // K half, head-major [bh][n][32]
            int b = rbase >> 10, n = (rbase & 1023) + r;
            int hh = m >> 5, dd = m & 31;
            ((__bf16*)outp)[(((size_t)b * 8 + hh) * 1024 + n) * 32 + dd] =
                (__bf16)v;
          } else if (MODE == 2) {
            size_t oi = (size_t)(rbase + r) * M + m;
            ((float*)outp)[oi] = e0[oi] + v + bias[m];
          } else if (MODE == 3) {
            ((float*)outp)[(size_t)(rbase + r) * M + m] = v + bias[m];
          } else if (MODE == 4) {
            v += bias[m];
            v = v * e2[m] + e3[m];
            ((__bf16*)outp)[(size_t)(rbase + r) * M + m] =
                (__bf16)(v >= 0.f ? v : a_pre * v);
          }
        }
      }
    }
  }
}

// ---------------------------------------------------------------- BN2
__global__ __launch_bounds__(256)
void bn2_stats_k(const float* __restrict__ xn2, float* __restrict__ raw) {
  int t = threadIdx.x;
  float s = 0.f, q = 0.f;
  int r0 = blockIdx.x * 128;
  for (int i = 0; i < 128; ++i) {
    float v = xn2[(size_t)(r0 + i) * C_DIM + t];
    s += v; q += v * v;
  }
  atomicAdd(&raw[t], s);
  atomicAdd(&raw[C_DIM + t], q);
}

__global__ __launch_bounds__(256)
void bn2_final_k(const float* __restrict__ raw, const float* __restrict__ g,
                 const float* __restrict__ bb, float* __restrict__ st) {
  int c = threadIdx.x;
  float mean = raw[c] * (1.f / 8192.f);
  float var  = raw[C_DIM + c] * (1.f / 8192.f) - mean * mean;
  float sc   = g[c] * rsqrtf(var + EPSV);
  st[c]         = sc;
  st[C_DIM + c] = bb[c] - mean * sc;
}

__global__ __launch_bounds__(256)
void bn2_apply_k(const float* __restrict__ xn2, const float* __restrict__ st,
                 __bf16* __restrict__ xb) {
  int i = blockIdx.x * 256 + threadIdx.x;
  float4 v = ((const float4*)xn2)[i];
  int c = (i * 4) & 255;
  ushort4 u;
  u.x = bfu(v.x * st[c]     + st[C_DIM + c]);
  u.y = bfu(v.y * st[c + 1] + st[C_DIM + c + 1]);
  u.z = bfu(v.z * st[c + 2] + st[C_DIM + c + 2]);
  u.w = bfu(v.w * st[c + 3] + st[C_DIM + c + 3]);
  ((ushort4*)xb)[i] = u;
}

extern "C" void kernel_launch(void* const* d_in, const int* in_sizes, int n_in,
                              void* d_out, int out_size, void* d_ws,
                              size_t ws_size, hipStream_t stream) {
  const float* x       = (const float*)d_in[0];
  const float* cor     = (const float*)d_in[1];
  const float* q_w     = (const float*)d_in[2];
  const float* kv_w    = (const float*)d_in[3];
  const float* cor_w   = (const float*)d_in[4];
  const float* proj_w  = (const float*)d_in[5];
  const float* proj_b  = (const float*)d_in[6];
  const float* mproj_w = (const float*)d_in[7];
  const float* mproj_b = (const float*)d_in[8];
  const float* g1      = (const float*)d_in[9];
  const float* b1      = (const float*)d_in[10];
  const float* g2      = (const float*)d_in[11];
  const float* b2      = (const float*)d_in[12];
  const float* fc1_w   = (const float*)d_in[13];
  const float* fc1_b   = (const float*)d_in[14];
  const float* dw_w    = (const float*)d_in[15];
  const float* dw_b    = (const float*)d_in[16];
  const float* prelu   = (const float*)d_in[17];
  const float* fc2_w   = (const float*)d_in[18];
  const float* fc2_b   = (const float*)d_in[19];

  char* base = (char*)d_ws;
  const size_t MB = 1u << 20;
  float*  xn32 = (float*)(base + 0);             // 0-8 MB  f32
  __bf16* xnb  = (__bf16*)(base + 8 * MB);       // 8-12
  __bf16* qb   = (__bf16*)(base + 12 * MB);      // 12-16  [bh][n][32]
  __bf16* kb   = (__bf16*)(base + 16 * MB);      // 16-20  [bh][n][32]
  __bf16* vt   = (__bf16*)(base + 20 * MB);      // 20-26  [bh][48][1024]
  __bf16* av   = (__bf16*)(base + 30 * MB);      // 30-34
  __bf16* dmc  = (__bf16*)(base + 34 * MB);      // 34-36
  float*  xn2  = (float*)(base + 36 * MB);       // 36-44 f32
  __bf16* xb   = (__bf16*)(base + 8 * MB);       // overlay xnb (dead post-kv)
  __bf16* hb   = (__bf16*)(base + 12 * MB);      // overlay 12-28 (fc1 out)
  __bf16* qwb  = (__bf16*)(base + 44 * MB);
  __bf16* kvwb = (__bf16*)(base + 44 * MB + 131072);
  __bf16* pwb  = (__bf16*)(base + 44 * MB + 393216);
  __bf16* mwb  = (__bf16*)(base + 44 * MB + 524288);
  __bf16* f1wb = (__bf16*)(base + 44 * MB + 557056);
  __bf16* f2wb = (__bf16*)(base + 44 * MB + 1081344);
  float*  st1  = (float*)(base + 45 * MB + 655360);
  float*  raw2 = st1 + 1024;
  float*  st2  = st1 + 2048;
  float* out0 = (float*)d_out;
  float* out1 = out0 + 2097152;

  hipMemsetAsync(raw2, 0, 512 * sizeof(float), stream);

  wcvt_k<<<784, 256, 0, stream>>>(q_w, kv_w, proj_w, mproj_w, fc1_w, fc2_w,
                                  qwb, kvwb, pwb, mwb, f1wb, f2wb);
  bn1_stats_k<<<256, 256, 0, stream>>>(x, g1, b1, st1);
  norm1_t_k<<<dim3(8, 32, 8), dim3(32, 8), 0, stream>>>(x, st1, xn32, xnb);

  // q = (xn @ q_w^T) * scale (bf16, head-major)
  mgemm_k<0, 64><<<dim3(4, 64), 256, 0, stream>>>(
      xnb, qwb, nullptr, qb, nullptr, nullptr, nullptr, nullptr, nullptr,
      256, 256);
  // kv = xr @ kv_w^T : K half -> kb head-major; V half -> vt transposed
  mgemm_k<1, 128><<<dim3(4, 64), 256, 0, stream>>>(
      xnb, kvwb, nullptr, kb, nullptr, nullptr, nullptr, nullptr, vt,
      256, 512);
  cet_k<<<dim3(64, 4), 256, 0, stream>>>(cor, cor_w, vt);

  attn_k<<<dim3(64, 8), 512, 0, stream>>>(qb, kb, vt, cor, cor_w, av, dmc);

  // xn2 = xn + av @ proj_w^T + proj_b (f32)
  mgemm_k<2, 64><<<dim3(4, 64), 256, 0, stream>>>(
      av, pwb, proj_b, xn2, xn32, nullptr, nullptr, nullptr, nullptr,
      256, 256);
  // motion = dmc @ mproj_w^T + mproj_b (f32, direct to out1)
  mgemm_k<3, 64><<<dim3(2, 64), 256, 0, stream>>>(
      dmc, mwb, mproj_b, out1, nullptr, nullptr, nullptr, nullptr, nullptr,
      128, 128);

  bn2_stats_k<<<64, 256, 0, stream>>>(xn2, raw2);
  bn2_final_k<<<1, 256, 0, stream>>>(raw2, g2, b2, st2);
  bn2_apply_k<<<2048, 256, 0, stream>>>(xn2, st2, xb);

  // h = prelu(dw(xb @ fc1_w^T + fc1_b)) (bf16)
  mgemm_k<4, 128><<<dim3(8, 64), 256, 0, stream>>>(
      xb, f1wb, fc1_b, hb, nullptr, dw_w, dw_b, prelu, nullptr, 256, HID_N);
  // x_out = x + (h @ fc2_w^T + fc2_b)^T (f32, transposed float4 store)
  mgemm_k<5, 64><<<dim3(4, 64), 256, 0, stream>>>(
      hb, f2wb, fc2_b, out0, x, nullptr, nullptr, nullptr, nullptr,
      HID_N, 256);
}

// Round 7
// 128.413 us; speedup vs baseline: 6.7667x; 1.1153x over previous
//
#include <hip/hip_runtime.h>
#include <hip/hip_bf16.h>
#include <math.h>

// MotionFormerBlock: bf16 MFMA GEMMs + swapped-operand MFMA flash attention.
// Shapes fixed: B=8, N=1024, C=DIM=256, MDIM=128, H=8, HD=32, MHD=16, HID=1024.
#define C_DIM 256
#define N_PTS 1024
#define H_N 8
#define MDIM_N 128
#define HID_N 1024
#define EPSV 1e-5f
#define R_TOT 8192
#define CN 262144               // C_DIM * N_PTS

typedef __bf16 bf16x8 __attribute__((ext_vector_type(8)));
typedef __bf16 bf16x4 __attribute__((ext_vector_type(4)));
typedef float f32x4 __attribute__((ext_vector_type(4)));

// softmax scale * log2(e): 32^-0.5 * 1.4426950408889634
#define QSCALE 0.25503482f

__device__ inline unsigned short bfu(float f) {
  union { __bf16 h; unsigned short u; } c;
  c.h = (__bf16)f;
  return c.u;
}

// ---------------------------------------------------------------- weight cvt
__global__ __launch_bounds__(256)
void wcvt_k(const float* __restrict__ s0, const float* __restrict__ s1,
            const float* __restrict__ s2, const float* __restrict__ s3,
            const float* __restrict__ s4, const float* __restrict__ s5,
            __bf16* d0, __bf16* d1, __bf16* d2, __bf16* d3, __bf16* d4,
            __bf16* d5) {
  int i = blockIdx.x * 256 + threadIdx.x;
  const float* s; __bf16* d; int off;
  if      (i <  16384) { s = s0; d = d0; off = 0; }
  else if (i <  49152) { s = s1; d = d1; off = 16384; }
  else if (i <  65536) { s = s2; d = d2; off = 49152; }
  else if (i <  69632) { s = s3; d = d3; off = 65536; }
  else if (i < 135168) { s = s4; d = d4; off = 69632; }
  else                 { s = s5; d = d5; off = 135168; }
  int j = i - off;
  float4 v = ((const float4*)s)[j];
  ushort4 u;
  u.x = bfu(v.x); u.y = bfu(v.y); u.z = bfu(v.z); u.w = bfu(v.w);
  ((ushort4*)d)[j] = u;
}

// ---------------------------------------------------------------- BN1 stats
__global__ __launch_bounds__(256)
void bn1_stats_k(const float* __restrict__ x, const float* __restrict__ g,
                 const float* __restrict__ bb, float* __restrict__ st) {
  int c = blockIdx.x;
  int t = threadIdx.x;
  float s = 0.f, q = 0.f;
  for (int i = 0; i < 32; ++i) {
    int idx = t + i * 256;
    int b = idx >> 10, n = idx & 1023;
    float v = x[(size_t)b * CN + (size_t)c * N_PTS + n];
    s += v; q += v * v;
  }
  __shared__ float ss[256], sq[256];
  ss[t] = s; sq[t] = q;
  __syncthreads();
  for (int off = 128; off > 0; off >>= 1) {
    if (t < off) { ss[t] += ss[t + off]; sq[t] += sq[t + off]; }
    __syncthreads();
  }
  if (t == 0) {
    float mean = ss[0] * (1.f / 8192.f);
    float var  = sq[0] * (1.f / 8192.f) - mean * mean;
    float sc   = g[c] * rsqrtf(var + EPSV);
    st[c]          = sc;
    st[C_DIM + c]  = bb[c] - mean * sc;
  }
}

// ------------------------------------------- normalize + transpose to tokens
__global__ __launch_bounds__(256)
void norm1_t_k(const float* __restrict__ x, const float* __restrict__ st,
               float* __restrict__ xn, __bf16* __restrict__ xnb) {
  __shared__ float tile[32][33];
  int c0 = blockIdx.x * 32, n0 = blockIdx.y * 32, b = blockIdx.z;
  int tx = threadIdx.x, ty = threadIdx.y;
#pragma unroll
  for (int k = 0; k < 4; ++k) {
    int ci = ty + k * 8;
    int c = c0 + ci;
    float v = x[(size_t)b * CN + (size_t)c * N_PTS + n0 + tx];
    tile[ci][tx] = v * st[c] + st[C_DIM + c];
  }
  __syncthreads();
#pragma unroll
  for (int k = 0; k < 4; ++k) {
    int ni = ty + k * 8;
    size_t o = ((size_t)(b * N_PTS + n0 + ni)) * C_DIM + c0 + tx;
    float v = tile[tx][ni];
    xn[o] = v;
    xnb[o] = (__bf16)v;
  }
}

// --------------------------------------- ceh transposed into vt rows 32..47
__global__ __launch_bounds__(256)
void cet_k(const float* __restrict__ cor, const float* __restrict__ cw,
           __bf16* __restrict__ vt) {
  __shared__ float cs[768];           // 256 tokens x 3
  int bh = blockIdx.x; int b = bh >> 3, h = bh & 7;
  int n0 = blockIdx.y * 256;
  int t = threadIdx.x;
  for (int i = t; i < 768; i += 256)
    cs[i] = cor[(size_t)(b * N_PTS + n0) * 3 + i];
  __syncthreads();
  int md = t >> 4, ns = (t & 15) * 16;
  float w0 = cw[(h * 16 + md) * 3 + 0];
  float w1 = cw[(h * 16 + md) * 3 + 1];
  float w2 = cw[(h * 16 + md) * 3 + 2];
  __bf16* dst = &vt[((size_t)bh * 48 + 32 + md) * 1024 + n0 + ns];
#pragma unroll
  for (int g2 = 0; g2 < 4; ++g2) {
    ushort4 u;
    float v0 = cs[(ns + g2 * 4 + 0) * 3] * w0 + cs[(ns + g2 * 4 + 0) * 3 + 1] * w1 + cs[(ns + g2 * 4 + 0) * 3 + 2] * w2;
    float v1 = cs[(ns + g2 * 4 + 1) * 3] * w0 + cs[(ns + g2 * 4 + 1) * 3 + 1] * w1 + cs[(ns + g2 * 4 + 1) * 3 + 2] * w2;
    float v2 = cs[(ns + g2 * 4 + 2) * 3] * w0 + cs[(ns + g2 * 4 + 2) * 3 + 1] * w1 + cs[(ns + g2 * 4 + 2) * 3 + 2] * w2;
    float v3 = cs[(ns + g2 * 4 + 3) * 3] * w0 + cs[(ns + g2 * 4 + 3) * 3 + 1] * w1 + cs[(ns + g2 * 4 + 3) * 3 + 2] * w2;
    u.x = bfu(v0); u.y = bfu(v1); u.z = bfu(v2); u.w = bfu(v3);
    *(ushort4*)&dst[g2 * 4] = u;
  }
}

// ---------------------------------------------------------------- MFMA attention
// 8 waves x 16 q-rows (512 thr), one (b,h) per blockIdx.x.
// SWAPPED operands: S^T = mfma(K, Q)  -> lane owns full row q=l15;
// softmax in-register (+2 shfl); O^T = mfma(V'^T, P) -> stats stay on-lane.
__global__ __launch_bounds__(512)
void attn_k(const __bf16* __restrict__ qb, const __bf16* __restrict__ kb,
            const __bf16* __restrict__ vt, const float* __restrict__ cor,
            const float* __restrict__ cw, __bf16* __restrict__ av,
            __bf16* __restrict__ dmc) {
  __shared__ __bf16 KsV[2][64][40];   // 10.2 KB
  __shared__ __bf16 VtV[2][48][72];   // 13.8 KB
  __shared__ __bf16 Pbuf[8][16][72];  // 18.4 KB  [wave][q][key]

  int bh = blockIdx.x; int b = bh >> 3, h = bh & 7;
  int t = threadIdx.x;
  int w = t >> 6, lane = t & 63;
  int l15 = lane & 15, g = lane >> 4;

  int nloc0 = blockIdx.y * 128 + w * 16;
  // Q fragment: lane holds Q[q=l15][d=g*8..+7] (B operand of S^T = K Q^T)
  bf16x8 aq =
      *(const bf16x8*)&qb[((size_t)bh * N_PTS + nloc0 + l15) * 32 + g * 8];

  const __bf16* ksrc = kb + (size_t)bh * N_PTS * 32;   // [1024][32]
  const __bf16* vsrc = vt + (size_t)bh * 48 * N_PTS;   // [48][1024]
  int u = t - 256;                // V-stage thread id (0..255)
  int vdv = u >> 3, vkg = u & 7;

  float mrun = -1e30f, lrun = 0.f;   // per-lane stats for q = l15
  f32x4 acco[3];                     // O^T: acco[mt][r] = O[q=l15][dv=16mt+4g+r]
#pragma unroll
  for (int mt = 0; mt < 3; ++mt) acco[mt] = (f32x4){0.f, 0.f, 0.f, 0.f};

  // prologue: stage tile 0 into buffer 0
  if (t < 256) {
    *(uint4*)&KsV[0][t >> 2][(t & 3) * 8] = *(const uint4*)&ksrc[t * 8];
  } else {
    *(uint4*)&VtV[0][vdv][vkg * 8] =
        *(const uint4*)&vsrc[(size_t)vdv * N_PTS + vkg * 8];
    if (u < 128)
      *(uint4*)&VtV[0][32 + vdv][vkg * 8] =
          *(const uint4*)&vsrc[(size_t)(32 + vdv) * N_PTS + vkg * 8];
  }
  __syncthreads();

  for (int kt = 0; kt < 16; ++kt) {
    int cur = kt & 1, nxt = cur ^ 1;
    // issue next-tile loads (consumed after compute)
    uint4 kreg, vreg0, vreg1;
    if (kt < 15) {
      int key1 = (kt + 1) * 64;
      if (t < 256) {
        kreg = *(const uint4*)&ksrc[key1 * 32 + t * 8];
      } else {
        vreg0 = *(const uint4*)&vsrc[(size_t)vdv * N_PTS + key1 + vkg * 8];
        if (u < 128)
          vreg1 =
              *(const uint4*)&vsrc[(size_t)(32 + vdv) * N_PTS + key1 + vkg * 8];
      }
    }

    // ---- S^T = K Q^T : sq[nt][r] = S[q=l15][key=16nt+4g+r] (log2e folded)
    f32x4 sq[4];
    __builtin_amdgcn_s_setprio(1);
#pragma unroll
    for (int nt = 0; nt < 4; ++nt) {
      bf16x8 kf = *(const bf16x8*)&KsV[cur][nt * 16 + l15][g * 8];
      f32x4 z = (f32x4){0.f, 0.f, 0.f, 0.f};
      sq[nt] = __builtin_amdgcn_mfma_f32_16x16x32_bf16(kf, aq, z, 0, 0, 0);
    }
    __builtin_amdgcn_s_setprio(0);

    // ---- softmax: in-register row reduce + 2 cross-lane swaps
    float tm = fmaxf(fmaxf(fmaxf(sq[0][0], sq[0][1]), fmaxf(sq[0][2], sq[0][3])),
                     fmaxf(fmaxf(sq[1][0], sq[1][1]), fmaxf(sq[1][2], sq[1][3])));
    tm = fmaxf(tm,
               fmaxf(fmaxf(fmaxf(sq[2][0], sq[2][1]), fmaxf(sq[2][2], sq[2][3])),
                     fmaxf(fmaxf(sq[3][0], sq[3][1]), fmaxf(sq[3][2], sq[3][3]))));
    tm = fmaxf(tm, __shfl_xor(tm, 16));
    tm = fmaxf(tm, __shfl_xor(tm, 32));
    float nm = fmaxf(mrun, tm);
    float corr = exp2f(mrun - nm);
    mrun = nm;
    float rs = 0.f;
#pragma unroll
    for (int nt = 0; nt < 4; ++nt)
#pragma unroll
      for (int r = 0; r < 4; ++r) {
        float p = exp2f(sq[nt][r] - nm);
        sq[nt][r] = p;
        rs += p;
      }
    rs += __shfl_xor(rs, 16);
    rs += __shfl_xor(rs, 32);
    lrun = lrun * corr + rs;
#pragma unroll
    for (int mt = 0; mt < 3; ++mt)
#pragma unroll
      for (int r = 0; r < 4; ++r) acco[mt][r] *= corr;

    // ---- pack P to LDS (4 x b64), reload as B fragments (2 x b128)
#pragma unroll
    for (int nt = 0; nt < 4; ++nt) {
      bf16x4 pk;
      pk[0] = (__bf16)sq[nt][0]; pk[1] = (__bf16)sq[nt][1];
      pk[2] = (__bf16)sq[nt][2]; pk[3] = (__bf16)sq[nt][3];
      *(bf16x4*)&Pbuf[w][l15][nt * 16 + g * 4] = pk;
    }
    bf16x8 ap[2];
#pragma unroll
    for (int kc = 0; kc < 2; ++kc)
      ap[kc] = *(const bf16x8*)&Pbuf[w][l15][kc * 32 + g * 8];

    // ---- O^T += V'^T P : A = V'-frag (same VtV reads), B = ap
    __builtin_amdgcn_s_setprio(1);
#pragma unroll
    for (int mt = 0; mt < 3; ++mt)
#pragma unroll
      for (int kc = 0; kc < 2; ++kc) {
        bf16x8 vf = *(const bf16x8*)&VtV[cur][mt * 16 + l15][kc * 32 + g * 8];
        acco[mt] = __builtin_amdgcn_mfma_f32_16x16x32_bf16(vf, ap[kc],
                                                           acco[mt], 0, 0, 0);
      }
    __builtin_amdgcn_s_setprio(0);

    // ---- write staged regs to the other buffer; one barrier per tile
    if (kt < 15) {
      if (t < 256) {
        *(uint4*)&KsV[nxt][t >> 2][(t & 3) * 8] = kreg;
      } else {
        *(uint4*)&VtV[nxt][vdv][vkg * 8] = vreg0;
        if (u < 128) *(uint4*)&VtV[nxt][32 + vdv][vkg * 8] = vreg1;
      }
      __syncthreads();
    }
  }

  // ---- epilogue: q = l15 row; packed ushort4 stores
  float inv = 1.f / lrun;
  int row = b * N_PTS + nloc0 + l15;
#pragma unroll
  for (int mt = 0; mt < 2; ++mt) {
    ushort4 o;
    o.x = bfu(acco[mt][0] * inv); o.y = bfu(acco[mt][1] * inv);
    o.z = bfu(acco[mt][2] * inv); o.w = bfu(acco[mt][3] * inv);
    *(ushort4*)&av[(size_t)row * C_DIM + h * 32 + mt * 16 + g * 4] = o;
  }
  {
    const float* cp = &cor[(size_t)row * 3];
    float c0 = cp[0], c1 = cp[1], c2 = cp[2];
    ushort4 o;
#pragma unroll
    for (int r = 0; r < 4; ++r) {
      int md = h * 16 + g * 4 + r;
      float ce = c0 * cw[md * 3] + c1 * cw[md * 3 + 1] + c2 * cw[md * 3 + 2];
      float v = acco[2][r] * inv - ce;
      ((unsigned short*)&o)[r] = bfu(v);
    }
    *(ushort4*)&dmc[(size_t)row * MDIM_N + h * 16 + g * 4] = o;
  }
}

// ---------------------------------------------------------------- MFMA GEMM
// MODE 0: out bf16 * QSCALE, head-major [bh][n][32] (q; log2e folded)
// MODE 1: A batch-swapped; m<256 -> kb head-major; m>=256 -> vt transposed
// MODE 2: out f32 = e0+acc+bias (proj->xn2)
// MODE 3: out f32 = acc+bias (motion)
// MODE 4: dw+PReLU epilogue, out bf16 (fc1)
// MODE 5: transposed float4 residual store (fc2)
template <int MODE, int BNt>
__global__ __launch_bounds__(256)
void mgemm_k(const __bf16* __restrict__ A, const __bf16* __restrict__ W,
             const float* __restrict__ bias, void* __restrict__ outp,
             const float* __restrict__ e0, const float* __restrict__ e2,
             const float* __restrict__ e3, const float* __restrict__ pre,
             __bf16* __restrict__ vtp, int K, int M) {
  constexpr int WN = BNt / 2;
  constexpr int NR = WN / 16;
  __shared__ __bf16 Al[128 * 64];
  __shared__ __bf16 Bl[BNt * 64];
  int t = threadIdx.x;
  int w = t >> 6, lane = t & 63;
  int l15 = lane & 15, g = lane >> 4;
  int wr = w >> 1, wn = w & 1;
  int r0 = blockIdx.y * 128;
  int m0 = blockIdx.x * BNt;

  f32x4 acc[4][NR];
#pragma unroll
  for (int i = 0; i < 4; ++i)
#pragma unroll
    for (int j = 0; j < NR; ++j) acc[i][j] = (f32x4){0.f, 0.f, 0.f, 0.f};

  for (int kt = 0; kt < K; kt += 64) {
    __syncthreads();
#pragma unroll
    for (int p = 0; p < 4; ++p) {
      int flat = p * 256 + t;
      int row = flat >> 3, c16 = flat & 7;
      int gr = r0 + row;
      if (MODE == 1) {
        int b = gr >> 10;
        gr = (((b + 4) & 7) << 10) | (gr & 1023);
      }
      *(uint4*)&Al[row * 64 + (c16 ^ (row & 7)) * 8] =
          *(const uint4*)&A[(size_t)gr * K + kt + c16 * 8];
    }
#pragma unroll
    for (int p = 0; p < BNt / 32; ++p) {
      int flat = p * 256 + t;
      int row = flat >> 3, c16 = flat & 7;
      *(uint4*)&Bl[row * 64 + (c16 ^ (row & 7)) * 8] =
          *(const uint4*)&W[(size_t)(m0 + row) * K + kt + c16 * 8];
    }
    __syncthreads();
#pragma unroll
    for (int ks = 0; ks < 2; ++ks) {
      bf16x8 af[4], bf_[NR];
#pragma unroll
      for (int mf = 0; mf < 4; ++mf) {
        int row = wr * 64 + mf * 16 + l15;
        af[mf] = *(const bf16x8*)&Al[row * 64 + ((ks * 4 + g) ^ (l15 & 7)) * 8];
      }
#pragma unroll
      for (int nf = 0; nf < NR; ++nf) {
        int row = wn * WN + nf * 16 + l15;
        bf_[nf] = *(const bf16x8*)&Bl[row * 64 + ((ks * 4 + g) ^ (l15 & 7)) * 8];
      }
#pragma unroll
      for (int mf = 0; mf < 4; ++mf)
#pragma unroll
        for (int nf = 0; nf < NR; ++nf)
          acc[mf][nf] = __builtin_amdgcn_mfma_f32_16x16x32_bf16(
              af[mf], bf_[nf], acc[mf][nf], 0, 0, 0);
    }
  }

  float a_pre = (MODE == 4) ? pre[0] : 0.f;
#pragma unroll
  for (int mf = 0; mf < 4; ++mf) {
#pragma unroll
    for (int nf = 0; nf < NR; ++nf) {
      int m = m0 + wn * WN + nf * 16 + l15;
      int rbase = r0 + wr * 64 + mf * 16 + g * 4;
      if (MODE == 5) {
        int b = rbase >> 10, n = rbase & 1023;
        size_t oi = (size_t)b * CN + (size_t)m * N_PTS + n;
        float4 xv = *(const float4*)&e0[oi];
        float bs = bias[m];
        float4 ov;
        ov.x = xv.x + acc[mf][nf][0] + bs;
        ov.y = xv.y + acc[mf][nf][1] + bs;
        ov.z = xv.z + acc[mf][nf][2] + bs;
        ov.w = xv.w + acc[mf][nf][3] + bs;
        *(float4*)&((float*)outp)[oi] = ov;
      } else if (MODE == 1 && m >= 256) {
        int d = m - 256, hh = d >> 5, dd = d & 31;
        int b = rbase >> 10, n0v = rbase & 1023;
        ushort4 uu;
        uu.x = bfu(acc[mf][nf][0]); uu.y = bfu(acc[mf][nf][1]);
        uu.z = bfu(acc[mf][nf][2]); uu.w = bfu(acc[mf][nf][3]);
        *(ushort4*)&vtp[(((size_t)b * 8 + hh) * 48 + dd) * 1024 + n0v] = uu;
      } else {
#pragma unroll
        for (int r = 0; r < 4; ++r) {
          float v = acc[mf][nf][r];
          if (MODE == 0) {
            int b = rbase >> 10, n = (rbase & 1023) + r;
            int hh = m >> 5, dd = m & 31;
            ((__bf16*)outp)[(((size_t)b * 8 + hh) * 1024 + n) * 32 + dd] =
                (__bf16)(v * QSCALE);
          } else if (MODE == 1) {
            int b = rbase >> 10, n = (rbase & 1023) + r;
            int hh = m >> 5, dd = m & 31;
            ((__bf16*)outp)[(((size_t)b * 8 + hh) * 1024 + n) * 32 + dd] =
                (__bf16)v;
          } else if (MODE == 2) {
            size_t oi = (size_t)(rbase + r) * M + m;
            ((float*)outp)[oi] = e0[oi] + v + bias[m];
          } else if (MODE == 3) {
            ((float*)outp)[(size_t)(rbase + r) * M + m] = v + bias[m];
          } else if (MODE == 4) {
            v += bias[m];
            v = v * e2[m] + e3[m];
            ((__bf16*)outp)[(size_t)(rbase + r) * M + m] =
                (__bf16)(v >= 0.f ? v : a_pre * v);
          }
        }
      }
    }
  }
}

// ---------------------------------------------------------------- BN2
__global__ __launch_bounds__(256)
void bn2_stats_k(const float* __restrict__ xn2, float* __restrict__ raw) {
  int t = threadIdx.x;
  float s = 0.f, q = 0.f;
  int r0 = blockIdx.x * 128;
  for (int i = 0; i < 128; ++i) {
    float v = xn2[(size_t)(r0 + i) * C_DIM + t];
    s += v; q += v * v;
  }
  atomicAdd(&raw[t], s);
  atomicAdd(&raw[C_DIM + t], q);
}

__global__ __launch_bounds__(256)
void bn2_final_k(const float* __restrict__ raw, const float* __restrict__ g,
                 const float* __restrict__ bb, float* __restrict__ st) {
  int c = threadIdx.x;
  float mean = raw[c] * (1.f / 8192.f);
  float var  = raw[C_DIM + c] * (1.f / 8192.f) - mean * mean;
  float sc   = g[c] * rsqrtf(var + EPSV);
  st[c]         = sc;
  st[C_DIM + c] = bb[c] - mean * sc;
}

__global__ __launch_bounds__(256)
void bn2_apply_k(const float* __restrict__ xn2, const float* __restrict__ st,
                 __bf16* __restrict__ xb) {
  int i = blockIdx.x * 256 + threadIdx.x;
  float4 v = ((const float4*)xn2)[i];
  int c = (i * 4) & 255;
  ushort4 u;
  u.x = bfu(v.x * st[c]     + st[C_DIM + c]);
  u.y = bfu(v.y * st[c + 1] + st[C_DIM + c + 1]);
  u.z = bfu(v.z * st[c + 2] + st[C_DIM + c + 2]);
  u.w = bfu(v.w * st[c + 3] + st[C_DIM + c + 3]);
  ((ushort4*)xb)[i] = u;
}

extern "C" void kernel_launch(void* const* d_in, const int* in_sizes, int n_in,
                              void* d_out, int out_size, void* d_ws,
                              size_t ws_size, hipStream_t stream) {
  const float* x       = (const float*)d_in[0];
  const float* cor     = (const float*)d_in[1];
  const float* q_w     = (const float*)d_in[2];
  const float* kv_w    = (const float*)d_in[3];
  const float* cor_w   = (const float*)d_in[4];
  const float* proj_w  = (const float*)d_in[5];
  const float* proj_b  = (const float*)d_in[6];
  const float* mproj_w = (const float*)d_in[7];
  const float* mproj_b = (const float*)d_in[8];
  const float* g1      = (const float*)d_in[9];
  const float* b1      = (const float*)d_in[10];
  const float* g2      = (const float*)d_in[11];
  const float* b2      = (const float*)d_in[12];
  const float* fc1_w   = (const float*)d_in[13];
  const float* fc1_b   = (const float*)d_in[14];
  const float* dw_w    = (const float*)d_in[15];
  const float* dw_b    = (const float*)d_in[16];
  const float* prelu   = (const float*)d_in[17];
  const float* fc2_w   = (const float*)d_in[18];
  const float* fc2_b   = (const float*)d_in[19];

  char* base = (char*)d_ws;
  const size_t MB = 1u << 20;
  float*  xn32 = (float*)(base + 0);             // 0-8 MB  f32
  __bf16* xnb  = (__bf16*)(base + 8 * MB);       // 8-12
  __bf16* qb   = (__bf16*)(base + 12 * MB);      // 12-16  [bh][n][32]
  __bf16* kb   = (__bf16*)(base + 16 * MB);      // 16-20  [bh][n][32]
  __bf16* vt   = (__bf16*)(base + 20 * MB);      // 20-26  [bh][48][1024]
  __bf16* av   = (__bf16*)(base + 30 * MB);      // 30-34
  __bf16* dmc  = (__bf16*)(base + 34 * MB);      // 34-36
  float*  xn2  = (float*)(base + 36 * MB);       // 36-44 f32
  __bf16* xb   = (__bf16*)(base + 8 * MB);       // overlay xnb (dead post-kv)
  __bf16* hb   = (__bf16*)(base + 12 * MB);      // overlay 12-28 (fc1 out)
  __bf16* qwb  = (__bf16*)(base + 44 * MB);
  __bf16* kvwb = (__bf16*)(base + 44 * MB + 131072);
  __bf16* pwb  = (__bf16*)(base + 44 * MB + 393216);
  __bf16* mwb  = (__bf16*)(base + 44 * MB + 524288);
  __bf16* f1wb = (__bf16*)(base + 44 * MB + 557056);
  __bf16* f2wb = (__bf16*)(base + 44 * MB + 1081344);
  float*  st1  = (float*)(base + 45 * MB + 655360);
  float*  raw2 = st1 + 1024;
  float*  st2  = st1 + 2048;
  float* out0 = (float*)d_out;
  float* out1 = out0 + 2097152;

  hipMemsetAsync(raw2, 0, 512 * sizeof(float), stream);

  wcvt_k<<<784, 256, 0, stream>>>(q_w, kv_w, proj_w, mproj_w, fc1_w, fc2_w,
                                  qwb, kvwb, pwb, mwb, f1wb, f2wb);
  bn1_stats_k<<<256, 256, 0, stream>>>(x, g1, b1, st1);
  norm1_t_k<<<dim3(8, 32, 8), dim3(32, 8), 0, stream>>>(x, st1, xn32, xnb);

  // q = (xn @ q_w^T) * scale*log2e (bf16, head-major)
  mgemm_k<0, 64><<<dim3(4, 64), 256, 0, stream>>>(
      xnb, qwb, nullptr, qb, nullptr, nullptr, nullptr, nullptr, nullptr,
      256, 256);
  // kv = xr @ kv_w^T : K half -> kb head-major; V half -> vt transposed
  mgemm_k<1, 128><<<dim3(4, 64), 256, 0, stream>>>(
      xnb, kvwb, nullptr, kb, nullptr, nullptr, nullptr, nullptr, vt,
      256, 512);
  cet_k<<<dim3(64, 4), 256, 0, stream>>>(cor, cor_w, vt);

  attn_k<<<dim3(64, 8), 512, 0, stream>>>(qb, kb, vt, cor, cor_w, av, dmc);

  // xn2 = xn + av @ proj_w^T + proj_b (f32)
  mgemm_k<2, 64><<<dim3(4, 64), 256, 0, stream>>>(
      av, pwb, proj_b, xn2, xn32, nullptr, nullptr, nullptr, nullptr,
      256, 256);
  // motion = dmc @ mproj_w^T + mproj_b (f32, direct to out1)
  mgemm_k<3, 64><<<dim3(2, 64), 256, 0, stream>>>(
      dmc, mwb, mproj_b, out1, nullptr, nullptr, nullptr, nullptr, nullptr,
      128, 128);

  bn2_stats_k<<<64, 256, 0, stream>>>(xn2, raw2);
  bn2_final_k<<<1, 256, 0, stream>>>(raw2, g2, b2, st2);
  bn2_apply_k<<<2048, 256, 0, stream>>>(xn2, st2, xb);

  // h = prelu(dw(xb @ fc1_w^T + fc1_b)) (bf16)
  mgemm_k<4, 128><<<dim3(8, 64), 256, 0, stream>>>(
      xb, f1wb, fc1_b, hb, nullptr, dw_w, dw_b, prelu, nullptr, 256, HID_N);
  // x_out = x + (h @ fc2_w^T + fc2_b)^T (f32, transposed float4 store)
  mgemm_k<5, 64><<<dim3(4, 64), 256, 0, stream>>>(
      hb, f2wb, fc2_b, out0, x, nullptr, nullptr, nullptr, nullptr,
      HID_N, 256);
}